// Round 10
// baseline (254.583 us; speedup 1.0000x reference)
//
#include <hip/hip_runtime.h>
#include <math.h>

// ---------------------------------------------------------------------------
// Transformer block (pre-LN). f32 in / f32 out (bf16-space comparison).
// Compute: bf16 MFMA, f32 accum. Workspace ~55.8 MiB.
// R25: attn v16 — wave-private K/V staging, barrier-free main loop.
//      R24 post-mortem: attn pinned at 44us since R18; counters close on a
//      convoy effect: per-iter barrier phase-locks 12 waves -> LDS storm
//      (1150cy) + VALU storm (1450cy) + MFMA run serially = 3300cy wall.
//      v16: each wave DMAs its own private double-buffered K-half (32x64)
//      + V-half (64x32) = 16KB/wave; no cross-wave LDS deps -> zero
//      barriers in the loop; waves de-phase and pipes overlap. Order per
//      iter: frag reads (vmcnt wait on own 1-iter-old DMA) -> issue next
//      DMA -> compute, so even a conservative drain is off-critical-path
//      (R19's failure mode avoided; LDS staging retained). V layout
//      [64][32] with (row>>1)&3 chunk swizzle (2-way = free); K mapping
//      unchanged. 2x K/V L2 reads (pair duplication) ~17TB/s << 34.5.
//      LDS 64KB -> 2 blocks/CU. Epilogue reduce unchanged (2 barriers).
//      GEMMs frozen at R24 (fc1 64x128 = 6/CU; R18 swizzle; proj/fc2 64x64).
// MFMA layouts (guide m89/m91/m92/m120):
//   A-frag:  A[m=lane&15][k=quad*8+j]
//   B-frag:  BT[n=lane&15][k=quad*8+j]
//   C/D:     row = quad*4 + reg, col = lane&15
// ---------------------------------------------------------------------------

typedef unsigned short u16;
typedef __attribute__((ext_vector_type(8))) short short8;   // 8 x bf16
typedef __attribute__((ext_vector_type(4))) float f32x4;

#define TOKENS 4096
#define DIM    768
#define QKV_N  2304
#define HID    3072
#define NSEQ   2048
#define NHEAD  12
#define HDIM   64

__device__ __forceinline__ float bf2f(u16 u) {
  union { unsigned i; float f; } v; v.i = ((unsigned)u) << 16; return v.f;
}
__device__ __forceinline__ u16 f2bf(float f) {
  union { float f; unsigned i; } v; v.f = f;
  unsigned r = v.i + 0x7fffu + ((v.i >> 16) & 1u);   // RNE
  return (u16)(r >> 16);
}
// v_cvt_pk_bf16_f32: dst.lo = bf16(lo), dst.hi = bf16(hi), RNE
__device__ __forceinline__ unsigned cvt_pk_bf16(float lo, float hi) {
  unsigned r;
  asm("v_cvt_pk_bf16_f32 %0, %1, %2" : "=v"(r) : "v"(lo), "v"(hi));
  return r;
}
// v_permlane32_swap_b32: a[32:63] <-> b[0:31]
__device__ __forceinline__ void pl32swap(unsigned &a, unsigned &b) {
  asm("v_permlane32_swap_b32 %0, %1" : "+v"(a), "+v"(b));
}
// v_permlane16_swap_b32: a's odd 16-rows <-> b's even 16-rows
__device__ __forceinline__ void pl16swap(unsigned &a, unsigned &b) {
  asm("v_permlane16_swap_b32 %0, %1" : "+v"(a), "+v"(b));
}

// async global->LDS, 16B/lane. LDS dest = wave-uniform base + lane*16 (m104).
__device__ __forceinline__ void async_copy16(const u16* g, u16* l) {
  __builtin_amdgcn_global_load_lds(
      (const __attribute__((address_space(1))) unsigned int*)(unsigned long long)g,
      (__attribute__((address_space(3))) unsigned int*)(unsigned int)(unsigned long long)l,
      16, 0, 0);
}

// ---- prep: 4 weight transposes + LN1, one dispatch --------------------------
// blocks 0..1023: LN1 (4 tokens each). blocks 1024..7935: 32x32 transposes.
__global__ __launch_bounds__(256) void prep_kernel(
    const float* __restrict__ x, const float* __restrict__ g,
    const float* __restrict__ b, u16* __restrict__ h,
    const float* __restrict__ in0, u16* __restrict__ out0,   // 768x2304
    const float* __restrict__ in1, u16* __restrict__ out1,   // 768x768
    const float* __restrict__ in2, u16* __restrict__ out2,   // 768x3072
    const float* __restrict__ in3, u16* __restrict__ out3) { // 3072x768
  const int tid = threadIdx.x;
  if (blockIdx.x < 1024) {
    // ---- LN1: one wave per token, f32 input ----
    int wave = tid >> 6, lane = tid & 63;
    int token = blockIdx.x * 4 + wave;
    float v[12];
    const float4* xr = (const float4*)(x + (size_t)token * DIM);
#pragma unroll
    for (int w = 0; w < 3; w++) {
      float4 q = xr[lane + w * 64];
      v[w * 4 + 0] = q.x; v[w * 4 + 1] = q.y; v[w * 4 + 2] = q.z; v[w * 4 + 3] = q.w;
    }
    float s = 0.f;
#pragma unroll
    for (int i = 0; i < 12; i++) s += v[i];
#pragma unroll
    for (int off = 32; off > 0; off >>= 1) s += __shfl_xor(s, off);
    float mu = s * (1.0f / DIM);
    float ss = 0.f;
#pragma unroll
    for (int i = 0; i < 12; i++) { float d = v[i] - mu; ss += d * d; }
#pragma unroll
    for (int off = 32; off > 0; off >>= 1) ss += __shfl_xor(ss, off);
    float rs = rsqrtf(ss * (1.0f / DIM) + 1e-5f);
    ushort4* orow = (ushort4*)(h + (size_t)token * DIM);
    const float4* g4 = (const float4*)g;
    const float4* b4 = (const float4*)b;
#pragma unroll
    for (int w = 0; w < 3; w++) {
      float4 gq = g4[lane + w * 64], bq = b4[lane + w * 64];
      ushort4 o;
      o.x = f2bf((v[w * 4 + 0] - mu) * rs * gq.x + bq.x);
      o.y = f2bf((v[w * 4 + 1] - mu) * rs * gq.y + bq.y);
      o.z = f2bf((v[w * 4 + 2] - mu) * rs * gq.z + bq.z);
      o.w = f2bf((v[w * 4 + 3] - mu) * rs * gq.w + bq.w);
      orow[lane + w * 64] = o;
    }
    return;
  }
  // ---- weight transpose ----
  __shared__ u16 t[32][33];
  int bid = blockIdx.x - 1024, rem;
  const float* in; u16* out; int R, C;
  if (bid < 1728)      { in = in0; out = out0; R = 768;  C = 2304; rem = bid; }
  else if (bid < 2304) { in = in1; out = out1; R = 768;  C = 768;  rem = bid - 1728; }
  else if (bid < 4608) { in = in2; out = out2; R = 768;  C = 3072; rem = bid - 2304; }
  else                 { in = in3; out = out3; R = 3072; C = 768;  rem = bid - 4608; }
  int c0 = (rem % (C / 32)) * 32, r0 = (rem / (C / 32)) * 32;
  int tx = tid & 31, ty = tid >> 5;
#pragma unroll
  for (int i = 0; i < 4; i++)
    t[ty + i * 8][tx] = f2bf(in[(size_t)(r0 + ty + i * 8) * C + c0 + tx]);
  __syncthreads();
#pragma unroll
  for (int i = 0; i < 4; i++)
    out[(size_t)(c0 + ty + i * 8) * R + r0 + tx] = t[tx][ty + i * 8];
}

// ---- LayerNorm (LN2): one wave per token, bf16 input -----------------------
__global__ __launch_bounds__(256) void ln_kernel(const u16* __restrict__ xin,
                                                 const float* __restrict__ g,
                                                 const float* __restrict__ b,
                                                 u16* __restrict__ out) {
  int wave = threadIdx.x >> 6, lane = threadIdx.x & 63;
  int token = blockIdx.x * 4 + wave;
  float v[12];
  const ushort4* xr = (const ushort4*)(xin + (size_t)token * DIM);
#pragma unroll
  for (int w = 0; w < 3; w++) {
    ushort4 q = xr[lane + w * 64];
    v[w * 4 + 0] = bf2f(q.x); v[w * 4 + 1] = bf2f(q.y);
    v[w * 4 + 2] = bf2f(q.z); v[w * 4 + 3] = bf2f(q.w);
  }
  float s = 0.f;
#pragma unroll
  for (int i = 0; i < 12; i++) s += v[i];
#pragma unroll
  for (int off = 32; off > 0; off >>= 1) s += __shfl_xor(s, off);
  float mu = s * (1.0f / DIM);
  float ss = 0.f;
#pragma unroll
  for (int i = 0; i < 12; i++) { float d = v[i] - mu; ss += d * d; }
#pragma unroll
  for (int off = 32; off > 0; off >>= 1) ss += __shfl_xor(ss, off);
  float rs = rsqrtf(ss * (1.0f / DIM) + 1e-5f);

  ushort4* orow = (ushort4*)(out + (size_t)token * DIM);
  const float4* g4 = (const float4*)g;
  const float4* b4 = (const float4*)b;
#pragma unroll
  for (int w = 0; w < 3; w++) {
    float4 gq = g4[lane + w * 64], bq = b4[lane + w * 64];
    ushort4 o;
    o.x = f2bf((v[w * 4 + 0] - mu) * rs * gq.x + bq.x);
    o.y = f2bf((v[w * 4 + 1] - mu) * rs * gq.y + bq.y);
    o.z = f2bf((v[w * 4 + 2] - mu) * rs * gq.z + bq.z);
    o.w = f2bf((v[w * 4 + 3] - mu) * rs * gq.w + bq.w);
    orow[lane + w * 64] = o;
  }
}

// ---- GEMM: C[M,N] = A[M,K] * BT[N,K]^T, bf16 in, fused epilogue ------------
// R13 structure: BK=64 as two stacked BK=32 panels, 2 barriers per iter.
// R18: bank-conflict-free LDS via pre-swizzled global source (rule #21):
//   LDS physical (row, pc) holds logical k-chunk pc ^ ((row>>1)&3); frag
//   reads fetch logical chunk quad at pc = quad ^ ((c16>>1)&3). Per 16-lane
//   phase, banks (row*16+pc*4)%32 cover all 8 groups twice -> 2-way (free).
// Flat grid, A-local XCD swizzle: by = b % (M/BM) (multiple of 8) -> all
// blocks sharing A-row-panels land on the same XCD; A stays in its L2.
// EPI: 0 = qkv: Q/K cols bf16 store; V cols (>=1536) packed transposed store
//      1 = +bias(f32) + resid(f32) -> bf16 store (proj -> x1 trunk)
//      2 = +bias(f32), exact gelu -> bf16 store (fc1)
//      3 = +bias(f32) + resid(bf16) -> F32 store (fc2 -> d_out)
template <int BM, int BN, int EPI>
__global__ __launch_bounds__(256, 3) void gemm_bt(
    const u16* __restrict__ A, const u16* __restrict__ BT,
    void* __restrict__ Cout, const float* __restrict__ bias,
    const void* __restrict__ resid, int M, int N, int K,
    u16* __restrict__ vtb) {
  constexpr int MT = BM / 32, NT = BN / 32;        // mfma tiles per wave
  constexpr int ACH = BM / 16;                     // A 16-row chunks per panel
  constexpr int CPW = (BM + BN) / 64;              // chunks per wave per panel
  __shared__ __align__(16) u16 Alds[2][BM * 32];   // two K-panels
  __shared__ __align__(16) u16 Blds[2][BN * 32];
  const int tid = threadIdx.x;
  const int lane = tid & 63, wave = tid >> 6;
  const int wr = wave >> 1, wc = wave & 1;
  const int nby = M / BM;                          // multiple of 8
  const int by = blockIdx.x % nby, bx = blockIdx.x / nby;
  const int bm = by * BM, bn = bx * BN;
  const int c16 = lane & 15, quad = lane >> 4;
  const int l4 = lane >> 2;
  // pre-swizzled source chunk: physical slot (row=l4, pc=lane&3) receives
  // logical k-chunk (lane&3) ^ ((l4>>1)&3)  [chunk*16 doesn't affect bits 1:2]
  const int lc = (((lane & 3) ^ ((l4 >> 1) & 3)) * 8);
  const int fsw = (c16 >> 1) & 3;                  // frag-read swizzle key

  f32x4 acc[MT][NT];
#pragma unroll
  for (int i = 0; i < MT; i++)
#pragma unroll
    for (int j = 0; j < NT; j++) acc[i][j] = (f32x4){0.f, 0.f, 0.f, 0.f};

  const u16* gsrc[CPW];
  u16* ldst[CPW];
  int hstep[CPW];                      // elems between panel 0 and 1 dests
#pragma unroll
  for (int c = 0; c < CPW; c++) {
    int chunk = wave * CPW + c;
    if (chunk < ACH) {
      gsrc[c] = A + (size_t)(bm + chunk * 16 + l4) * K + lc;
      ldst[c] = Alds[0] + chunk * 512;
      hstep[c] = BM * 32;
    } else {
      int bc = chunk - ACH;
      gsrc[c] = BT + (size_t)(bn + bc * 16 + l4) * K + lc;
      ldst[c] = Blds[0] + bc * 512;
      hstep[c] = BN * 32;
    }
  }

  for (int kk = 0; kk < K; kk += 64) {
    __syncthreads();                    // prior iteration's frag reads done
#pragma unroll
    for (int c = 0; c < CPW; c++) {
      async_copy16(gsrc[c] + kk, ldst[c]);
      async_copy16(gsrc[c] + kk + 32, ldst[c] + hstep[c]);
    }
    __syncthreads();                    // barrier drains vmcnt (LDS visible)
#pragma unroll
    for (int ks = 0; ks < 2; ks++) {
      short8 af[MT], bfr[NT];
#pragma unroll
      for (int mt = 0; mt < MT; mt++)
        af[mt] = *(const short8*)(Alds[ks] + (wr * (BM / 2) + mt * 16 + c16) * 32 +
                                  ((quad ^ fsw)) * 8);
#pragma unroll
      for (int nt = 0; nt < NT; nt++)
        bfr[nt] = *(const short8*)(Blds[ks] + (wc * (BN / 2) + nt * 16 + c16) * 32 +
                                   ((quad ^ fsw)) * 8);
#pragma unroll
      for (int mt = 0; mt < MT; mt++)
#pragma unroll
        for (int nt = 0; nt < NT; nt++)
          acc[mt][nt] = __builtin_amdgcn_mfma_f32_16x16x32_bf16(af[mt], bfr[nt],
                                                                acc[mt][nt], 0, 0, 0);
    }
  }

#pragma unroll
  for (int mt = 0; mt < MT; mt++) {
#pragma unroll
    for (int nt = 0; nt < NT; nt++) {
      int col = bn + wc * (BN / 2) + nt * 16 + c16;
      float bv = (EPI != 0) ? bias[col] : 0.f;
      int row0 = bm + wr * (BM / 2) + mt * 16 + quad * 4;
      if (EPI == 0 && col >= 2 * DIM) {
        // V columns: packed transposed store vt[(b*768+hd)][tok] (tok=row)
        int b = row0 >> 11;
        ushort4 pk;
        pk.x = f2bf(acc[mt][nt][0]); pk.y = f2bf(acc[mt][nt][1]);
        pk.z = f2bf(acc[mt][nt][2]); pk.w = f2bf(acc[mt][nt][3]);
        *(ushort4*)(vtb + ((size_t)b * DIM + col - 2 * DIM) * NSEQ + (row0 & 2047)) = pk;
        continue;
      }
#pragma unroll
      for (int r = 0; r < 4; r++) {
        int row = row0 + r;
        float vv = acc[mt][nt][r];
        if (EPI == 1) {
          vv += bv + ((const float*)resid)[(size_t)row * N + col];
          ((u16*)Cout)[(size_t)row * N + col] = f2bf(vv);
        } else if (EPI == 2) {
          vv += bv;
          vv = 0.5f * vv * (1.0f + erff(vv * 0.70710678118654752f));
          ((u16*)Cout)[(size_t)row * N + col] = f2bf(vv);
        } else if (EPI == 3) {
          vv += bv + bf2f(((const u16*)resid)[(size_t)row * N + col]);
          ((float*)Cout)[(size_t)row * N + col] = vv;     // f32 final output
        } else {
          ((u16*)Cout)[(size_t)row * N + col] = f2bf(vv);
        }
      }
    }
  }
}

// ---- flash attention v16: wave-private staging, barrier-free main loop -----
// Grid/head-major XCD swizzle unchanged (24 | blocks). Block = 4 waves over a
// 64-row q-tile; wave (wq,wk): wq -> 32 q-rows, wk -> 32-key half. Each wave
// DMAs its OWN double-buffered K-half [32 key][64 d] and V-half [64 d][32 key]
// (16KB/wave): no cross-wave LDS deps -> no barriers in the loop; per-iter
// order = frag reads (vmcnt wait on own 1-iter-old DMA) -> issue next-tile
// DMA -> compute. K chunk-swizzle pc=quad^(c16&7) (rows 128B, as before);
// V rows are 64B so pc=quad^((c16>>1)&3) gives 2-way (free). S^T = mfma(K,Q);
// P via cvt_pk + permlane swaps (in-register transpose). Epilogue: wk-pair
// O/L reduce via LDS scratch (reuses Kp/Vp), two barriers.
__global__ __launch_bounds__(256, 3) void attn_kernel(const u16* __restrict__ qkv,
                                                      const u16* __restrict__ vt,
                                                      u16* __restrict__ o) {
  const int tid = threadIdx.x;
  const int lane = tid & 63, wave = tid >> 6;      // wave 0..3
  const int c16 = lane & 15, quad = lane >> 4;
  const int wq = wave >> 1, wk = wave & 1;         // q-half / key-half
  const int bh = blockIdx.x % (2 * NHEAD);         // head-major (XCD locality)
  const int qt = blockIdx.x / (2 * NHEAD);
  const int bb = bh / NHEAD, h = bh % NHEAD;
  // wave-private double-buffered staging: 16KB/wave, 64KB/block
  __shared__ __align__(16) u16 Kp[4][2][32 * 64];  // [wave][buf][key][d] swz
  __shared__ __align__(16) u16 Vp[4][2][64 * 32];  // [wave][buf][d][key] swz
  const size_t base = (size_t)bb * NSEQ * QKV_N;
  const int q0 = qt * 64;
  const int sw = c16 & 7;                          // K chunk-swizzle key
  const int vsw = (c16 >> 1) & 3;                  // V chunk-swizzle key

  // Q frags (B-operand): lane holds Q[q0+wq*32+qs*16+c16][ch*32+quad*8+j]
  short8 qf[2][2];
#pragma unroll
  for (int qs = 0; qs < 2; qs++) {
    const u16* qp = qkv + base + (size_t)(q0 + wq * 32 + qs * 16 + c16) * QKV_N + h * HDIM;
    qf[qs][0] = *(const short8*)(qp + quad * 8);
    qf[qs][1] = *(const short8*)(qp + 32 + quad * 8);
  }

  float Ls[2] = {0.f, 0.f};
  f32x4 Of[2][4];
#pragma unroll
  for (int qs = 0; qs < 2; qs++)
#pragma unroll
    for (int dt = 0; dt < 4; dt++) Of[qs][dt] = (f32x4){0.f, 0.f, 0.f, 0.f};

  // per-lane staging sources (this wave's halves only):
  // K copy j: rows wk*32 + j*8 + (lane>>3), d-chunk (lane&7)^(lane>>3)
  const int l8 = lane >> 3;
  const u16* ksrc = qkv + base + (size_t)(wk * 32 + l8) * QKV_N + DIM + h * HDIM +
                    (((lane & 7) ^ l8) * 8);
  // V copy j: d-rows j*16 + (lane>>2), key-chunk (lane&3)^((lane>>3)&3)
  const u16* vsrc = vt + ((size_t)bh * HDIM + (lane >> 2)) * NSEQ + wk * 32 +
                    (((lane & 3) ^ ((lane >> 3) & 3)) * 8);
  u16* kw = &Kp[wave][0][0];                       // buf stride 2048 elems
  u16* vw = &Vp[wave][0][0];
  const float SC = 0.18033688011112042f;           // 0.125 * log2(e)

  // prologue: stage tile 0 into buf 0 (8 wave-private copies)
#pragma unroll
  for (int j = 0; j < 4; j++) {
    async_copy16(ksrc + (size_t)(j * 8) * QKV_N, kw + j * 512);
    async_copy16(vsrc + (size_t)(j * 16) * NSEQ, vw + j * 512);
  }
  const u16* ksn = ksrc + (size_t)64 * QKV_N;      // next-tile running ptrs
  const u16* vsn = vsrc + 64;

  for (int it = 0; it < NSEQ / 64; it++) {
    const int cur = it & 1;
    const u16* Kw = kw + cur * 2048;
    const u16* Vw = vw + cur * 2048;

    // K frags (A-operand): local keys kt*16 + c16 (compiler inserts the
    // vmcnt wait for this wave's own 1-iter-old DMA here)
    short8 kf0[2], kf1[2];
#pragma unroll
    for (int kt = 0; kt < 2; kt++) {
      const u16* krow = Kw + (kt * 16 + c16) * 64;
      kf0[kt] = *(const short8*)(krow + (quad ^ sw) * 8);
      kf1[kt] = *(const short8*)(krow + ((quad + 4) ^ sw) * 8);
    }
    // V frags: rows d = dt*16 + c16, local key-chunk quad
    short8 vf[4];
#pragma unroll
    for (int dt = 0; dt < 4; dt++)
      vf[dt] = *(const short8*)(Vw + (dt * 16 + c16) * 32 + (quad ^ vsw) * 8);

    // issue next tile's DMA into buf cur^1 (wave-private: no barrier)
    if (it + 1 < NSEQ / 64) {
      u16* kd = kw + (cur ^ 1) * 2048;
      u16* vd = vw + (cur ^ 1) * 2048;
#pragma unroll
      for (int j = 0; j < 4; j++) {
        async_copy16(ksn + (size_t)(j * 8) * QKV_N, kd + j * 512);
        async_copy16(vsn + (size_t)(j * 16) * NSEQ, vd + j * 512);
      }
      ksn += (size_t)64 * QKV_N;
      vsn += 64;
    }

    // S^T[key][q]: row = key local (kt*16+quad*4+r), col = q (c16)
    f32x4 St[2][2];
#pragma unroll
    for (int qs = 0; qs < 2; qs++)
#pragma unroll
      for (int kt = 0; kt < 2; kt++) {
        f32x4 s = (f32x4){0.f, 0.f, 0.f, 0.f};
        s = __builtin_amdgcn_mfma_f32_16x16x32_bf16(kf0[kt], qf[qs][0], s, 0, 0, 0);
        s = __builtin_amdgcn_mfma_f32_16x16x32_bf16(kf1[kt], qf[qs][1], s, 0, 0, 0);
        St[qs][kt] = s;
      }

    // softmax + in-register P->A-frag transpose (quad dim only):
    //   pl32swap: a<->b across lane halves; pl16swap: odd<->even 16-rows
    //   result dwords: D0=a0, D1=a1, D2=b0, D3=b1 = keys {8q..8q+7} of row c16
    short8 pf[2];
#pragma unroll
    for (int qs = 0; qs < 2; qs++) {
      float p[2][4];
#pragma unroll
      for (int kt = 0; kt < 2; kt++)
#pragma unroll
        for (int r = 0; r < 4; r++)
          p[kt][r] = __builtin_amdgcn_exp2f(St[qs][kt][r] * SC);
      Ls[qs] += ((p[0][0] + p[0][1]) + (p[0][2] + p[0][3])) +
                ((p[1][0] + p[1][1]) + (p[1][2] + p[1][3]));
      unsigned a0 = cvt_pk_bf16(p[0][0], p[0][1]);
      unsigned a1 = cvt_pk_bf16(p[0][2], p[0][3]);
      unsigned b0 = cvt_pk_bf16(p[1][0], p[1][1]);
      unsigned b1 = cvt_pk_bf16(p[1][2], p[1][3]);
      pl32swap(a0, b0);
      pl32swap(a1, b1);
      pl16swap(a0, b0);
      pl16swap(a1, b1);
      union { unsigned u[4]; short8 s; } pk_;
      pk_.u[0] = a0; pk_.u[1] = a1; pk_.u[2] = b0; pk_.u[3] = b1;
      pf[qs] = pk_.s;
    }

    // PV: A = P[16q x 32keys local], B^T = Vt[d][key] frags
#pragma unroll
    for (int dt = 0; dt < 4; dt++)
#pragma unroll
      for (int qs = 0; qs < 2; qs++)
        Of[qs][dt] = __builtin_amdgcn_mfma_f32_16x16x32_bf16(pf[qs], vf[dt],
                                                             Of[qs][dt], 0, 0, 0);
  }

  // ---- cross-wave (wk) reduction of O,L; normalize + store (wk==0) ---------
  __syncthreads();                     // all waves done with private bufs
  float* red = (float*)&Kp[0][0][0];   // 16 KB scratch: wk==1 partial O
  float* lred = (float*)&Vp[0][0][0];  // 1 KB scratch: wk==1 partial L
  if (wk == 1) {
    float* dst = red + wq * 2048;
#pragma unroll
    for (int qs = 0; qs < 2; qs++)
#pragma unroll
      for (int dt = 0; dt < 4; dt++)
        *(f32x4*)(dst + (qs * 4 + dt) * 256 + lane * 4) = Of[qs][dt];
    lred[wq * 128 + lane] = Ls[0];
    lred[wq * 128 + 64 + lane] = Ls[1];
  }
  __syncthreads();
  if (wk == 0) {
    const float* src = red + wq * 2048;
#pragma unroll
    for (int qs = 0; qs < 2; qs++)
#pragma unroll
      for (int dt = 0; dt < 4; dt++)
        Of[qs][dt] += *(const f32x4*)(src + (qs * 4 + dt) * 256 + lane * 4);
    float t0 = Ls[0] + lred[wq * 128 + lane];
    float t1 = Ls[1] + lred[wq * 128 + 64 + lane];
    // row totals: sum the 4 quad-partials (keys split across quads)
    t0 += __shfl_xor(t0, 16); t0 += __shfl_xor(t0, 32);
    t1 += __shfl_xor(t1, 16); t1 += __shfl_xor(t1, 32);
#pragma unroll
    for (int qs = 0; qs < 2; qs++) {
      float tq = qs ? t1 : t0;
#pragma unroll
      for (int r = 0; r < 4; r++) {
        float L = __shfl(tq, quad * 4 + r);    // row total lives at lane c16=row
        int token = q0 + wq * 32 + qs * 16 + quad * 4 + r;
        u16* orow = o + (size_t)(bb * NSEQ + token) * DIM + h * HDIM;
#pragma unroll
        for (int dt = 0; dt < 4; dt++)
          orow[dt * 16 + c16] = f2bf(Of[qs][dt][r] / L);
      }
    }
  }
}

// ---------------------------------------------------------------------------
extern "C" void kernel_launch(void* const* d_in, const int* in_sizes, int n_in,
                              void* d_out, int out_size, void* d_ws, size_t ws_size,
                              hipStream_t stream) {
  (void)in_sizes; (void)n_in; (void)out_size; (void)ws_size;
  const float* x      = (const float*)d_in[0];
  const float* ln1_g  = (const float*)d_in[1];
  const float* ln1_b  = (const float*)d_in[2];
  const float* w_qkv  = (const float*)d_in[3];
  const float* w_proj = (const float*)d_in[4];
  const float* b_proj = (const float*)d_in[5];
  const float* ln2_g  = (const float*)d_in[6];
  const float* ln2_b  = (const float*)d_in[7];
  const float* w_fc1  = (const float*)d_in[8];
  const float* b_fc1  = (const float*)d_in[9];
  const float* w_fc2  = (const float*)d_in[10];
  const float* b_fc2  = (const float*)d_in[11];
  float* out = (float*)d_out;   // f32 output (reference dtype)

  // ---- workspace layout: ~55.8 MiB total ----
  char* p = (char*)d_ws;
  u16* h_bf   = (u16*)p; p += (size_t)TOKENS * DIM * 2;     //  h, then h2
  u16* qkv_bf = (u16*)p; p += (size_t)TOKENS * QKV_N * 2;
  u16* o_bf   = (u16*)p; p += (size_t)TOKENS * DIM * 2;
  u16* x1_bf  = (u16*)p; p += (size_t)TOKENS * DIM * 2;     //  trunk
  u16* wprojT = (u16*)p; p += (size_t)DIM * DIM * 2;
  u16* wfc1T  = (u16*)p; p += (size_t)HID * DIM * 2;
  u16* wfc2T  = (u16*)p; p += (size_t)DIM * HID * 2;
  u16* wqkvT  = (u16*)p; p += (size_t)QKV_N * DIM * 2;
  u16* vtb    = (u16*)p; p += (size_t)TOKENS * DIM * 2;     //  V transposed
  u16* m_bf   = qkv_bf;  // fc1 out [4096,3072] overlays dead [qkv|o] exactly

  prep_kernel<<<dim3(1024 + 6912), 256, 0, stream>>>(
      x, ln1_g, ln1_b, h_bf,
      w_qkv, wqkvT, w_proj, wprojT, w_fc1, wfc1T, w_fc2, wfc2T);

  gemm_bt<64, 128, 0><<<dim3((QKV_N / 128) * (TOKENS / 64)), 256, 0, stream>>>(
      h_bf, wqkvT, qkv_bf, nullptr, nullptr, TOKENS, QKV_N, DIM, vtb);
  attn_kernel<<<dim3(2 * NHEAD * (NSEQ / 64)), 256, 0, stream>>>(qkv_bf, vtb, o_bf);
  gemm_bt<64, 64, 1><<<dim3((DIM / 64) * (TOKENS / 64)), 256, 0, stream>>>(
      o_bf, wprojT, x1_bf, b_proj, x, TOKENS, DIM, DIM, nullptr);
  ln_kernel<<<TOKENS / 4, 256, 0, stream>>>(x1_bf, ln2_g, ln2_b, h_bf);
  gemm_bt<64, 128, 2><<<dim3((HID / 128) * (TOKENS / 64)), 256, 0, stream>>>(
      h_bf, wfc1T, m_bf, b_fc1, nullptr, TOKENS, HID, DIM, nullptr);
  gemm_bt<64, 64, 3><<<dim3((DIM / 64) * (TOKENS / 64)), 256, 0, stream>>>(
      m_bf, wfc2T, out, b_fc2, x1_bf, TOKENS, DIM, HID, nullptr);
}

// Round 11
// 246.488 us; speedup vs baseline: 1.0328x; 1.0328x over previous
//
#include <hip/hip_runtime.h>
#include <math.h>

// ---------------------------------------------------------------------------
// Transformer block (pre-LN). f32 in / f32 out (bf16-space comparison).
// Compute: bf16 MFMA, f32 accum. Workspace ~55.8 MiB.
// R26: revert attn to v12r (R24 build; v16 wave-private staging regressed
//      44->53.6us via occupancy loss 3->2 blocks/CU, and absmax crept to
//      0.113). GEMM gains NP template param (panels per stage round):
//      fc2 -> NP=4 (BK=128). Theory: fc2 is first-touch HBM-latency bound
//      (A=m_bf 25MB not L2-resident; per-round wall 1885cy vs 140cy
//      compute; 1-round dbuf lookahead barely covers ~900cy latency).
//      BK=128 quadruples lookahead cycles and halves barrier rounds
//      (48->24); fc2 occupancy unchanged (grid-limited 3/CU, 32KB LDS x3
//      fits). fc1 stays NP=2 (48KB would cut its 6 blocks/CU -> R24 win).
// MFMA layouts (guide m89/m91/m92/m120):
//   A-frag:  A[m=lane&15][k=quad*8+j]
//   B-frag:  BT[n=lane&15][k=quad*8+j]
//   C/D:     row = quad*4 + reg, col = lane&15
// ---------------------------------------------------------------------------

typedef unsigned short u16;
typedef __attribute__((ext_vector_type(8))) short short8;   // 8 x bf16
typedef __attribute__((ext_vector_type(4))) float f32x4;

#define TOKENS 4096
#define DIM    768
#define QKV_N  2304
#define HID    3072
#define NSEQ   2048
#define NHEAD  12
#define HDIM   64

__device__ __forceinline__ float bf2f(u16 u) {
  union { unsigned i; float f; } v; v.i = ((unsigned)u) << 16; return v.f;
}
__device__ __forceinline__ u16 f2bf(float f) {
  union { float f; unsigned i; } v; v.f = f;
  unsigned r = v.i + 0x7fffu + ((v.i >> 16) & 1u);   // RNE
  return (u16)(r >> 16);
}
// v_cvt_pk_bf16_f32: dst.lo = bf16(lo), dst.hi = bf16(hi), RNE
__device__ __forceinline__ unsigned cvt_pk_bf16(float lo, float hi) {
  unsigned r;
  asm("v_cvt_pk_bf16_f32 %0, %1, %2" : "=v"(r) : "v"(lo), "v"(hi));
  return r;
}
// v_permlane32_swap_b32: a[32:63] <-> b[0:31]
__device__ __forceinline__ void pl32swap(unsigned &a, unsigned &b) {
  asm("v_permlane32_swap_b32 %0, %1" : "+v"(a), "+v"(b));
}
// v_permlane16_swap_b32: a's odd 16-rows <-> b's even 16-rows
__device__ __forceinline__ void pl16swap(unsigned &a, unsigned &b) {
  asm("v_permlane16_swap_b32 %0, %1" : "+v"(a), "+v"(b));
}

// async global->LDS, 16B/lane. LDS dest = wave-uniform base + lane*16 (m104).
__device__ __forceinline__ void async_copy16(const u16* g, u16* l) {
  __builtin_amdgcn_global_load_lds(
      (const __attribute__((address_space(1))) unsigned int*)(unsigned long long)g,
      (__attribute__((address_space(3))) unsigned int*)(unsigned int)(unsigned long long)l,
      16, 0, 0);
}

// ---- prep: 4 weight transposes + LN1, one dispatch --------------------------
// blocks 0..1023: LN1 (4 tokens each). blocks 1024..7935: 32x32 transposes.
__global__ __launch_bounds__(256) void prep_kernel(
    const float* __restrict__ x, const float* __restrict__ g,
    const float* __restrict__ b, u16* __restrict__ h,
    const float* __restrict__ in0, u16* __restrict__ out0,   // 768x2304
    const float* __restrict__ in1, u16* __restrict__ out1,   // 768x768
    const float* __restrict__ in2, u16* __restrict__ out2,   // 768x3072
    const float* __restrict__ in3, u16* __restrict__ out3) { // 3072x768
  const int tid = threadIdx.x;
  if (blockIdx.x < 1024) {
    // ---- LN1: one wave per token, f32 input ----
    int wave = tid >> 6, lane = tid & 63;
    int token = blockIdx.x * 4 + wave;
    float v[12];
    const float4* xr = (const float4*)(x + (size_t)token * DIM);
#pragma unroll
    for (int w = 0; w < 3; w++) {
      float4 q = xr[lane + w * 64];
      v[w * 4 + 0] = q.x; v[w * 4 + 1] = q.y; v[w * 4 + 2] = q.z; v[w * 4 + 3] = q.w;
    }
    float s = 0.f;
#pragma unroll
    for (int i = 0; i < 12; i++) s += v[i];
#pragma unroll
    for (int off = 32; off > 0; off >>= 1) s += __shfl_xor(s, off);
    float mu = s * (1.0f / DIM);
    float ss = 0.f;
#pragma unroll
    for (int i = 0; i < 12; i++) { float d = v[i] - mu; ss += d * d; }
#pragma unroll
    for (int off = 32; off > 0; off >>= 1) ss += __shfl_xor(ss, off);
    float rs = rsqrtf(ss * (1.0f / DIM) + 1e-5f);
    ushort4* orow = (ushort4*)(h + (size_t)token * DIM);
    const float4* g4 = (const float4*)g;
    const float4* b4 = (const float4*)b;
#pragma unroll
    for (int w = 0; w < 3; w++) {
      float4 gq = g4[lane + w * 64], bq = b4[lane + w * 64];
      ushort4 o;
      o.x = f2bf((v[w * 4 + 0] - mu) * rs * gq.x + bq.x);
      o.y = f2bf((v[w * 4 + 1] - mu) * rs * gq.y + bq.y);
      o.z = f2bf((v[w * 4 + 2] - mu) * rs * gq.z + bq.z);
      o.w = f2bf((v[w * 4 + 3] - mu) * rs * gq.w + bq.w);
      orow[lane + w * 64] = o;
    }
    return;
  }
  // ---- weight transpose ----
  __shared__ u16 t[32][33];
  int bid = blockIdx.x - 1024, rem;
  const float* in; u16* out; int R, C;
  if (bid < 1728)      { in = in0; out = out0; R = 768;  C = 2304; rem = bid; }
  else if (bid < 2304) { in = in1; out = out1; R = 768;  C = 768;  rem = bid - 1728; }
  else if (bid < 4608) { in = in2; out = out2; R = 768;  C = 3072; rem = bid - 2304; }
  else                 { in = in3; out = out3; R = 3072; C = 768;  rem = bid - 4608; }
  int c0 = (rem % (C / 32)) * 32, r0 = (rem / (C / 32)) * 32;
  int tx = tid & 31, ty = tid >> 5;
#pragma unroll
  for (int i = 0; i < 4; i++)
    t[ty + i * 8][tx] = f2bf(in[(size_t)(r0 + ty + i * 8) * C + c0 + tx]);
  __syncthreads();
#pragma unroll
  for (int i = 0; i < 4; i++)
    out[(size_t)(c0 + ty + i * 8) * R + r0 + tx] = t[tx][ty + i * 8];
}

// ---- LayerNorm (LN2): one wave per token, bf16 input -----------------------
__global__ __launch_bounds__(256) void ln_kernel(const u16* __restrict__ xin,
                                                 const float* __restrict__ g,
                                                 const float* __restrict__ b,
                                                 u16* __restrict__ out) {
  int wave = threadIdx.x >> 6, lane = threadIdx.x & 63;
  int token = blockIdx.x * 4 + wave;
  float v[12];
  const ushort4* xr = (const ushort4*)(xin + (size_t)token * DIM);
#pragma unroll
  for (int w = 0; w < 3; w++) {
    ushort4 q = xr[lane + w * 64];
    v[w * 4 + 0] = bf2f(q.x); v[w * 4 + 1] = bf2f(q.y);
    v[w * 4 + 2] = bf2f(q.z); v[w * 4 + 3] = bf2f(q.w);
  }
  float s = 0.f;
#pragma unroll
  for (int i = 0; i < 12; i++) s += v[i];
#pragma unroll
  for (int off = 32; off > 0; off >>= 1) s += __shfl_xor(s, off);
  float mu = s * (1.0f / DIM);
  float ss = 0.f;
#pragma unroll
  for (int i = 0; i < 12; i++) { float d = v[i] - mu; ss += d * d; }
#pragma unroll
  for (int off = 32; off > 0; off >>= 1) ss += __shfl_xor(ss, off);
  float rs = rsqrtf(ss * (1.0f / DIM) + 1e-5f);

  ushort4* orow = (ushort4*)(out + (size_t)token * DIM);
  const float4* g4 = (const float4*)g;
  const float4* b4 = (const float4*)b;
#pragma unroll
  for (int w = 0; w < 3; w++) {
    float4 gq = g4[lane + w * 64], bq = b4[lane + w * 64];
    ushort4 o;
    o.x = f2bf((v[w * 4 + 0] - mu) * rs * gq.x + bq.x);
    o.y = f2bf((v[w * 4 + 1] - mu) * rs * gq.y + bq.y);
    o.z = f2bf((v[w * 4 + 2] - mu) * rs * gq.z + bq.z);
    o.w = f2bf((v[w * 4 + 3] - mu) * rs * gq.w + bq.w);
    orow[lane + w * 64] = o;
  }
}

// ---- GEMM: C[M,N] = A[M,K] * BT[N,K]^T, bf16 in, fused epilogue ------------
// R13 structure: NP stacked BK=32 panels per stage round, 2 barriers/round.
// R18: bank-conflict-free LDS via pre-swizzled global source (rule #21):
//   LDS physical (row, pc) holds logical k-chunk pc ^ ((row>>1)&3); frag
//   reads fetch logical chunk quad at pc = quad ^ ((c16>>1)&3). Per 16-lane
//   phase, banks (row*16+pc*4)%32 cover all 8 groups twice -> 2-way (free).
// R26: NP template param. NP=2 (BK=64) default; fc2 uses NP=4 (BK=128) --
//   4x prefetch lookahead to cover first-touch HBM latency, half the
//   barrier rounds; occupancy unchanged (grid-limited).
// Flat grid, A-local XCD swizzle: by = b % (M/BM) (multiple of 8) -> all
// blocks sharing A-row-panels land on the same XCD; A stays in its L2.
// EPI: 0 = qkv: Q/K cols bf16 store; V cols (>=1536) packed transposed store
//      1 = +bias(f32) + resid(f32) -> bf16 store (proj -> x1 trunk)
//      2 = +bias(f32), exact gelu -> bf16 store (fc1)
//      3 = +bias(f32) + resid(bf16) -> F32 store (fc2 -> d_out)
template <int BM, int BN, int EPI, int NP>
__global__ __launch_bounds__(256, 3) void gemm_bt(
    const u16* __restrict__ A, const u16* __restrict__ BT,
    void* __restrict__ Cout, const float* __restrict__ bias,
    const void* __restrict__ resid, int M, int N, int K,
    u16* __restrict__ vtb) {
  constexpr int MT = BM / 32, NT = BN / 32;        // mfma tiles per wave
  constexpr int ACH = BM / 16;                     // A 16-row chunks per panel
  constexpr int CPW = (BM + BN) / 64;              // chunks per wave per panel
  __shared__ __align__(16) u16 Alds[NP][BM * 32];  // NP K-panels
  __shared__ __align__(16) u16 Blds[NP][BN * 32];
  const int tid = threadIdx.x;
  const int lane = tid & 63, wave = tid >> 6;
  const int wr = wave >> 1, wc = wave & 1;
  const int nby = M / BM;                          // multiple of 8
  const int by = blockIdx.x % nby, bx = blockIdx.x / nby;
  const int bm = by * BM, bn = bx * BN;
  const int c16 = lane & 15, quad = lane >> 4;
  const int l4 = lane >> 2;
  // pre-swizzled source chunk: physical slot (row=l4, pc=lane&3) receives
  // logical k-chunk (lane&3) ^ ((l4>>1)&3)  [chunk*16 doesn't affect bits 1:2]
  const int lc = (((lane & 3) ^ ((l4 >> 1) & 3)) * 8);
  const int fsw = (c16 >> 1) & 3;                  // frag-read swizzle key

  f32x4 acc[MT][NT];
#pragma unroll
  for (int i = 0; i < MT; i++)
#pragma unroll
    for (int j = 0; j < NT; j++) acc[i][j] = (f32x4){0.f, 0.f, 0.f, 0.f};

  const u16* gsrc[CPW];
  u16* ldst[CPW];
  int hstep[CPW];                      // elems between panel p and p+1 dests
#pragma unroll
  for (int c = 0; c < CPW; c++) {
    int chunk = wave * CPW + c;
    if (chunk < ACH) {
      gsrc[c] = A + (size_t)(bm + chunk * 16 + l4) * K + lc;
      ldst[c] = Alds[0] + chunk * 512;
      hstep[c] = BM * 32;
    } else {
      int bc = chunk - ACH;
      gsrc[c] = BT + (size_t)(bn + bc * 16 + l4) * K + lc;
      ldst[c] = Blds[0] + bc * 512;
      hstep[c] = BN * 32;
    }
  }

  for (int kk = 0; kk < K; kk += 32 * NP) {
    __syncthreads();                    // prior round's frag reads done
#pragma unroll
    for (int c = 0; c < CPW; c++)
#pragma unroll
      for (int p = 0; p < NP; p++)
        async_copy16(gsrc[c] + kk + 32 * p, ldst[c] + p * hstep[c]);
    __syncthreads();                    // barrier drains vmcnt (LDS visible)
#pragma unroll
    for (int ks = 0; ks < NP; ks++) {
      short8 af[MT], bfr[NT];
#pragma unroll
      for (int mt = 0; mt < MT; mt++)
        af[mt] = *(const short8*)(Alds[ks] + (wr * (BM / 2) + mt * 16 + c16) * 32 +
                                  ((quad ^ fsw)) * 8);
#pragma unroll
      for (int nt = 0; nt < NT; nt++)
        bfr[nt] = *(const short8*)(Blds[ks] + (wc * (BN / 2) + nt * 16 + c16) * 32 +
                                   ((quad ^ fsw)) * 8);
#pragma unroll
      for (int mt = 0; mt < MT; mt++)
#pragma unroll
        for (int nt = 0; nt < NT; nt++)
          acc[mt][nt] = __builtin_amdgcn_mfma_f32_16x16x32_bf16(af[mt], bfr[nt],
                                                                acc[mt][nt], 0, 0, 0);
    }
  }

#pragma unroll
  for (int mt = 0; mt < MT; mt++) {
#pragma unroll
    for (int nt = 0; nt < NT; nt++) {
      int col = bn + wc * (BN / 2) + nt * 16 + c16;
      float bv = (EPI != 0) ? bias[col] : 0.f;
      int row0 = bm + wr * (BM / 2) + mt * 16 + quad * 4;
      if (EPI == 0 && col >= 2 * DIM) {
        // V columns: packed transposed store vt[(b*768+hd)][tok] (tok=row)
        int b = row0 >> 11;
        ushort4 pk;
        pk.x = f2bf(acc[mt][nt][0]); pk.y = f2bf(acc[mt][nt][1]);
        pk.z = f2bf(acc[mt][nt][2]); pk.w = f2bf(acc[mt][nt][3]);
        *(ushort4*)(vtb + ((size_t)b * DIM + col - 2 * DIM) * NSEQ + (row0 & 2047)) = pk;
        continue;
      }
#pragma unroll
      for (int r = 0; r < 4; r++) {
        int row = row0 + r;
        float vv = acc[mt][nt][r];
        if (EPI == 1) {
          vv += bv + ((const float*)resid)[(size_t)row * N + col];
          ((u16*)Cout)[(size_t)row * N + col] = f2bf(vv);
        } else if (EPI == 2) {
          vv += bv;
          vv = 0.5f * vv * (1.0f + erff(vv * 0.70710678118654752f));
          ((u16*)Cout)[(size_t)row * N + col] = f2bf(vv);
        } else if (EPI == 3) {
          vv += bv + bf2f(((const u16*)resid)[(size_t)row * N + col]);
          ((float*)Cout)[(size_t)row * N + col] = vv;     // f32 final output
        } else {
          ((u16*)Cout)[(size_t)row * N + col] = f2bf(vv);
        }
      }
    }
  }
}

// ---- flash attention v12r: split-K wave pairs + in-register P (cvt_pk) -----
// Grid/head-major XCD swizzle unchanged (24 | blocks). Block = 4 waves over a
// 64-row q-tile; wave (wq,wk): wq -> 32 q-rows, wk -> 32-key half of each
// 64-key tile. S^T = mfma(K,Q): lane (c16,quad) holds P[q=c16][kt*16+quad*4+r].
// PV A-frag needs P[q=c16][quad*8+j] -- a 4x4 transpose in the quad dim only:
// cvt_pk pairs to dwords, then 2x permlane32_swap + 2x permlane16_swap (VALU
// pipe, no LDS). Per-wave DS per iter: 4 K-frag + 4 V-frag b128 reads only.
// Partial O (32q x 64d) and L summed across the wk pair via LDS at the end.
__global__ __launch_bounds__(256, 3) void attn_kernel(const u16* __restrict__ qkv,
                                                      const u16* __restrict__ vt,
                                                      u16* __restrict__ o) {
  const int tid = threadIdx.x;
  const int lane = tid & 63, wave = tid >> 6;      // wave 0..3
  const int c16 = lane & 15, quad = lane >> 4;
  const int wq = wave >> 1, wk = wave & 1;         // q-half / key-half
  const int bh = blockIdx.x % (2 * NHEAD);         // head-major (XCD locality)
  const int qt = blockIdx.x / (2 * NHEAD);
  const int bb = bh / NHEAD, h = bh % NHEAD;
  __shared__ __align__(16) u16 Klds[2][64 * 64];   // [buf][key][d] swizzled
  __shared__ __align__(16) u16 Vtlds[2][64 * 64];  // [buf][d][key] swizzled
  const size_t base = (size_t)bb * NSEQ * QKV_N;
  const int q0 = qt * 64;
  const int sw = c16 & 7;                          // K/V chunk-swizzle key

  // Q frags (B-operand): lane holds Q[q0+wq*32+qs*16+c16][ch*32+quad*8+j]
  short8 qf[2][2];
#pragma unroll
  for (int qs = 0; qs < 2; qs++) {
    const u16* qp = qkv + base + (size_t)(q0 + wq * 32 + qs * 16 + c16) * QKV_N + h * HDIM;
    qf[qs][0] = *(const short8*)(qp + quad * 8);
    qf[qs][1] = *(const short8*)(qp + 32 + quad * 8);
  }

  float Ls[2] = {0.f, 0.f};
  f32x4 Of[2][4];
#pragma unroll
  for (int qs = 0; qs < 2; qs++)
#pragma unroll
    for (int dt = 0; dt < 4; dt++) Of[qs][dt] = (f32x4){0.f, 0.f, 0.f, 0.f};

  // staging: each wave stages 16 K-rows + 16 Vt-rows per tile (unchanged)
  const int srow = lane >> 3;
  const int schunk = (lane & 7) ^ srow;
  const int r0 = wave * 16;
  const u16* ksrc = qkv + base + (size_t)(r0 + srow) * QKV_N + DIM + h * HDIM + schunk * 8;
  const u16* vsrc = vt + ((size_t)bh * HDIM + r0 + srow) * NSEQ + schunk * 8;
  const float SC = 0.18033688011112042f;           // 0.125 * log2(e)

  // prologue: stage tile 0 into buffer 0
#pragma unroll
  for (int j = 0; j < 2; j++) {
    async_copy16(ksrc + (size_t)(8 * j) * QKV_N, Klds[0] + r0 * 64 + 8 * j * 64);
    async_copy16(vsrc + (size_t)(8 * j) * NSEQ, Vtlds[0] + r0 * 64 + 8 * j * 64);
  }

  for (int it = 0; it < NSEQ / 64; it++) {
    const int cur = it & 1;
    __syncthreads();   // drains DMA(it) + all waves done reading buf cur^1
    if (it + 1 < NSEQ / 64) {
      const int kt1 = (it + 1) * 64;
      u16* kd = Klds[cur ^ 1] + r0 * 64;
      u16* vd = Vtlds[cur ^ 1] + r0 * 64;
#pragma unroll
      for (int j = 0; j < 2; j++) {
        async_copy16(ksrc + (size_t)(kt1 + 8 * j) * QKV_N, kd + 8 * j * 64);
        async_copy16(vsrc + (size_t)(8 * j) * NSEQ + kt1, vd + 8 * j * 64);
      }
    }

    // K frags (A-operand): keys wk*32 + kt*16 + c16, this wave's half only
    short8 kf0[2], kf1[2];
#pragma unroll
    for (int kt = 0; kt < 2; kt++) {
      const u16* krow = Klds[cur] + (wk * 32 + kt * 16 + c16) * 64;
      kf0[kt] = *(const short8*)(krow + (quad ^ sw) * 8);
      kf1[kt] = *(const short8*)(krow + ((quad + 4) ^ sw) * 8);
    }

    // S^T[key][q]: row = key local (kt*16+quad*4+r), col = q (c16)
    f32x4 St[2][2];
#pragma unroll
    for (int qs = 0; qs < 2; qs++)
#pragma unroll
      for (int kt = 0; kt < 2; kt++) {
        f32x4 s = (f32x4){0.f, 0.f, 0.f, 0.f};
        s = __builtin_amdgcn_mfma_f32_16x16x32_bf16(kf0[kt], qf[qs][0], s, 0, 0, 0);
        s = __builtin_amdgcn_mfma_f32_16x16x32_bf16(kf1[kt], qf[qs][1], s, 0, 0, 0);
        St[qs][kt] = s;
      }

    // V frags early (independent of softmax): keys wk*32 + quad*8 + j
    short8 vf[4];
#pragma unroll
    for (int dt = 0; dt < 4; dt++) {
      const u16* vrow = Vtlds[cur] + (dt * 16 + c16) * 64;
      vf[dt] = *(const short8*)(vrow + ((wk * 4 + quad) ^ sw) * 8);
    }

    // softmax + in-register P->A-frag transpose (quad dim only):
    //   pl32swap: a<->b across lane halves; pl16swap: odd<->even 16-rows
    //   result dwords: D0=a0, D1=a1, D2=b0, D3=b1 = keys {8q..8q+7} of row c16
    short8 pf[2];
#pragma unroll
    for (int qs = 0; qs < 2; qs++) {
      float p[2][4];
#pragma unroll
      for (int kt = 0; kt < 2; kt++)
#pragma unroll
        for (int r = 0; r < 4; r++)
          p[kt][r] = __builtin_amdgcn_exp2f(St[qs][kt][r] * SC);
      Ls[qs] += ((p[0][0] + p[0][1]) + (p[0][2] + p[0][3])) +
                ((p[1][0] + p[1][1]) + (p[1][2] + p[1][3]));
      unsigned a0 = cvt_pk_bf16(p[0][0], p[0][1]);
      unsigned a1 = cvt_pk_bf16(p[0][2], p[0][3]);
      unsigned b0 = cvt_pk_bf16(p[1][0], p[1][1]);
      unsigned b1 = cvt_pk_bf16(p[1][2], p[1][3]);
      pl32swap(a0, b0);
      pl32swap(a1, b1);
      pl16swap(a0, b0);
      pl16swap(a1, b1);
      union { unsigned u[4]; short8 s; } pk_;
      pk_.u[0] = a0; pk_.u[1] = a1; pk_.u[2] = b0; pk_.u[3] = b1;
      pf[qs] = pk_.s;
    }

    // PV: A = P[16q x 32keys local], B^T = Vt[d][key] frags
#pragma unroll
    for (int dt = 0; dt < 4; dt++)
#pragma unroll
      for (int qs = 0; qs < 2; qs++)
        Of[qs][dt] = __builtin_amdgcn_mfma_f32_16x16x32_bf16(pf[qs], vf[dt],
                                                             Of[qs][dt], 0, 0, 0);
  }

  // ---- cross-wave (wk) reduction of O,L; normalize + store (wk==0) ---------
  __syncthreads();                     // all waves done with K/V LDS reads
  float* red = (float*)&Klds[0][0];    // 16 KB: wk==1 waves' partial O
  float* lred = (float*)&Vtlds[0][0];  // 1 KB: wk==1 waves' partial L
  if (wk == 1) {
    float* dst = red + wq * 2048;
#pragma unroll
    for (int qs = 0; qs < 2; qs++)
#pragma unroll
      for (int dt = 0; dt < 4; dt++)
        *(f32x4*)(dst + (qs * 4 + dt) * 256 + lane * 4) = Of[qs][dt];
    lred[wq * 128 + lane] = Ls[0];
    lred[wq * 128 + 64 + lane] = Ls[1];
  }
  __syncthreads();
  if (wk == 0) {
    const float* src = red + wq * 2048;
#pragma unroll
    for (int qs = 0; qs < 2; qs++)
#pragma unroll
      for (int dt = 0; dt < 4; dt++)
        Of[qs][dt] += *(const f32x4*)(src + (qs * 4 + dt) * 256 + lane * 4);
    float t0 = Ls[0] + lred[wq * 128 + lane];
    float t1 = Ls[1] + lred[wq * 128 + 64 + lane];
    // row totals: sum the 4 quad-partials (keys split across quads)
    t0 += __shfl_xor(t0, 16); t0 += __shfl_xor(t0, 32);
    t1 += __shfl_xor(t1, 16); t1 += __shfl_xor(t1, 32);
#pragma unroll
    for (int qs = 0; qs < 2; qs++) {
      float tq = qs ? t1 : t0;
#pragma unroll
      for (int r = 0; r < 4; r++) {
        float L = __shfl(tq, quad * 4 + r);    // row total lives at lane c16=row
        int token = q0 + wq * 32 + qs * 16 + quad * 4 + r;
        u16* orow = o + (size_t)(bb * NSEQ + token) * DIM + h * HDIM;
#pragma unroll
        for (int dt = 0; dt < 4; dt++)
          orow[dt * 16 + c16] = f2bf(Of[qs][dt][r] / L);
      }
    }
  }
}

// ---------------------------------------------------------------------------
extern "C" void kernel_launch(void* const* d_in, const int* in_sizes, int n_in,
                              void* d_out, int out_size, void* d_ws, size_t ws_size,
                              hipStream_t stream) {
  (void)in_sizes; (void)n_in; (void)out_size; (void)ws_size;
  const float* x      = (const float*)d_in[0];
  const float* ln1_g  = (const float*)d_in[1];
  const float* ln1_b  = (const float*)d_in[2];
  const float* w_qkv  = (const float*)d_in[3];
  const float* w_proj = (const float*)d_in[4];
  const float* b_proj = (const float*)d_in[5];
  const float* ln2_g  = (const float*)d_in[6];
  const float* ln2_b  = (const float*)d_in[7];
  const float* w_fc1  = (const float*)d_in[8];
  const float* b_fc1  = (const float*)d_in[9];
  const float* w_fc2  = (const float*)d_in[10];
  const float* b_fc2  = (const float*)d_in[11];
  float* out = (float*)d_out;   // f32 output (reference dtype)

  // ---- workspace layout: ~55.8 MiB total ----
  char* p = (char*)d_ws;
  u16* h_bf   = (u16*)p; p += (size_t)TOKENS * DIM * 2;     //  h, then h2
  u16* qkv_bf = (u16*)p; p += (size_t)TOKENS * QKV_N * 2;
  u16* o_bf   = (u16*)p; p += (size_t)TOKENS * DIM * 2;
  u16* x1_bf  = (u16*)p; p += (size_t)TOKENS * DIM * 2;     //  trunk
  u16* wprojT = (u16*)p; p += (size_t)DIM * DIM * 2;
  u16* wfc1T  = (u16*)p; p += (size_t)HID * DIM * 2;
  u16* wfc2T  = (u16*)p; p += (size_t)DIM * HID * 2;
  u16* wqkvT  = (u16*)p; p += (size_t)QKV_N * DIM * 2;
  u16* vtb    = (u16*)p; p += (size_t)TOKENS * DIM * 2;     //  V transposed
  u16* m_bf   = qkv_bf;  // fc1 out [4096,3072] overlays dead [qkv|o] exactly

  prep_kernel<<<dim3(1024 + 6912), 256, 0, stream>>>(
      x, ln1_g, ln1_b, h_bf,
      w_qkv, wqkvT, w_proj, wprojT, w_fc1, wfc1T, w_fc2, wfc2T);

  gemm_bt<64, 128, 0, 2><<<dim3((QKV_N / 128) * (TOKENS / 64)), 256, 0, stream>>>(
      h_bf, wqkvT, qkv_bf, nullptr, nullptr, TOKENS, QKV_N, DIM, vtb);
  attn_kernel<<<dim3(2 * NHEAD * (NSEQ / 64)), 256, 0, stream>>>(qkv_bf, vtb, o_bf);
  gemm_bt<64, 64, 1, 2><<<dim3((DIM / 64) * (TOKENS / 64)), 256, 0, stream>>>(
      o_bf, wprojT, x1_bf, b_proj, x, TOKENS, DIM, DIM, nullptr);
  ln_kernel<<<TOKENS / 4, 256, 0, stream>>>(x1_bf, ln2_g, ln2_b, h_bf);
  gemm_bt<64, 128, 2, 2><<<dim3((HID / 128) * (TOKENS / 64)), 256, 0, stream>>>(
      h_bf, wfc1T, m_bf, b_fc1, nullptr, TOKENS, HID, DIM, nullptr);
  gemm_bt<64, 64, 3, 4><<<dim3((DIM / 64) * (TOKENS / 64)), 256, 0, stream>>>(
      m_bf, wfc2T, out, b_fc2, x1_bf, TOKENS, DIM, HID, nullptr);
}

// Round 12
// 240.804 us; speedup vs baseline: 1.0572x; 1.0236x over previous
//
#include <hip/hip_runtime.h>
#include <math.h>

// ---------------------------------------------------------------------------
// Transformer block (pre-LN). f32 in / f32 out (bf16-space comparison).
// Compute: bf16 MFMA, f32 accum. Workspace ~55.8 MiB.
// R27: GEMM DB (double-buffer) path for proj/fc2. R26 post-mortem: NP=4
//      lookahead was neutral -> GEMM's stall is structural: it issues DMAs
//      then immediately barrier-drains them (full latency exposed/round).
//      DB=1 mirrors attn v12's proven loop: one barrier/round, issue round
//      r+1 into buf^1, compute round r -> drain happens a full round after
//      issue (latency hidden). Safe only where LDS 2x keeps occupancy:
//      proj/fc2 64x64 16->32KB at launch-bound 3 blocks/CU. qkv (24KB,
//      4.5/CU) and fc1 (24KB, 6/CU = R24 win) stay DB=0. fc2 NP 4->2.
//      attn v12r frozen (43.5us, absmax 0.03125).
// MFMA layouts (guide m89/m91/m92/m120):
//   A-frag:  A[m=lane&15][k=quad*8+j]
//   B-frag:  BT[n=lane&15][k=quad*8+j]
//   C/D:     row = quad*4 + reg, col = lane&15
// ---------------------------------------------------------------------------

typedef unsigned short u16;
typedef __attribute__((ext_vector_type(8))) short short8;   // 8 x bf16
typedef __attribute__((ext_vector_type(4))) float f32x4;

#define TOKENS 4096
#define DIM    768
#define QKV_N  2304
#define HID    3072
#define NSEQ   2048
#define NHEAD  12
#define HDIM   64

__device__ __forceinline__ float bf2f(u16 u) {
  union { unsigned i; float f; } v; v.i = ((unsigned)u) << 16; return v.f;
}
__device__ __forceinline__ u16 f2bf(float f) {
  union { float f; unsigned i; } v; v.f = f;
  unsigned r = v.i + 0x7fffu + ((v.i >> 16) & 1u);   // RNE
  return (u16)(r >> 16);
}
// v_cvt_pk_bf16_f32: dst.lo = bf16(lo), dst.hi = bf16(hi), RNE
__device__ __forceinline__ unsigned cvt_pk_bf16(float lo, float hi) {
  unsigned r;
  asm("v_cvt_pk_bf16_f32 %0, %1, %2" : "=v"(r) : "v"(lo), "v"(hi));
  return r;
}
// v_permlane32_swap_b32: a[32:63] <-> b[0:31]
__device__ __forceinline__ void pl32swap(unsigned &a, unsigned &b) {
  asm("v_permlane32_swap_b32 %0, %1" : "+v"(a), "+v"(b));
}
// v_permlane16_swap_b32: a's odd 16-rows <-> b's even 16-rows
__device__ __forceinline__ void pl16swap(unsigned &a, unsigned &b) {
  asm("v_permlane16_swap_b32 %0, %1" : "+v"(a), "+v"(b));
}

// async global->LDS, 16B/lane. LDS dest = wave-uniform base + lane*16 (m104).
__device__ __forceinline__ void async_copy16(const u16* g, u16* l) {
  __builtin_amdgcn_global_load_lds(
      (const __attribute__((address_space(1))) unsigned int*)(unsigned long long)g,
      (__attribute__((address_space(3))) unsigned int*)(unsigned int)(unsigned long long)l,
      16, 0, 0);
}

// ---- prep: 4 weight transposes + LN1, one dispatch --------------------------
// blocks 0..1023: LN1 (4 tokens each). blocks 1024..7935: 32x32 transposes.
__global__ __launch_bounds__(256) void prep_kernel(
    const float* __restrict__ x, const float* __restrict__ g,
    const float* __restrict__ b, u16* __restrict__ h,
    const float* __restrict__ in0, u16* __restrict__ out0,   // 768x2304
    const float* __restrict__ in1, u16* __restrict__ out1,   // 768x768
    const float* __restrict__ in2, u16* __restrict__ out2,   // 768x3072
    const float* __restrict__ in3, u16* __restrict__ out3) { // 3072x768
  const int tid = threadIdx.x;
  if (blockIdx.x < 1024) {
    // ---- LN1: one wave per token, f32 input ----
    int wave = tid >> 6, lane = tid & 63;
    int token = blockIdx.x * 4 + wave;
    float v[12];
    const float4* xr = (const float4*)(x + (size_t)token * DIM);
#pragma unroll
    for (int w = 0; w < 3; w++) {
      float4 q = xr[lane + w * 64];
      v[w * 4 + 0] = q.x; v[w * 4 + 1] = q.y; v[w * 4 + 2] = q.z; v[w * 4 + 3] = q.w;
    }
    float s = 0.f;
#pragma unroll
    for (int i = 0; i < 12; i++) s += v[i];
#pragma unroll
    for (int off = 32; off > 0; off >>= 1) s += __shfl_xor(s, off);
    float mu = s * (1.0f / DIM);
    float ss = 0.f;
#pragma unroll
    for (int i = 0; i < 12; i++) { float d = v[i] - mu; ss += d * d; }
#pragma unroll
    for (int off = 32; off > 0; off >>= 1) ss += __shfl_xor(ss, off);
    float rs = rsqrtf(ss * (1.0f / DIM) + 1e-5f);
    ushort4* orow = (ushort4*)(h + (size_t)token * DIM);
    const float4* g4 = (const float4*)g;
    const float4* b4 = (const float4*)b;
#pragma unroll
    for (int w = 0; w < 3; w++) {
      float4 gq = g4[lane + w * 64], bq = b4[lane + w * 64];
      ushort4 o;
      o.x = f2bf((v[w * 4 + 0] - mu) * rs * gq.x + bq.x);
      o.y = f2bf((v[w * 4 + 1] - mu) * rs * gq.y + bq.y);
      o.z = f2bf((v[w * 4 + 2] - mu) * rs * gq.z + bq.z);
      o.w = f2bf((v[w * 4 + 3] - mu) * rs * gq.w + bq.w);
      orow[lane + w * 64] = o;
    }
    return;
  }
  // ---- weight transpose ----
  __shared__ u16 t[32][33];
  int bid = blockIdx.x - 1024, rem;
  const float* in; u16* out; int R, C;
  if (bid < 1728)      { in = in0; out = out0; R = 768;  C = 2304; rem = bid; }
  else if (bid < 2304) { in = in1; out = out1; R = 768;  C = 768;  rem = bid - 1728; }
  else if (bid < 4608) { in = in2; out = out2; R = 768;  C = 3072; rem = bid - 2304; }
  else                 { in = in3; out = out3; R = 3072; C = 768;  rem = bid - 4608; }
  int c0 = (rem % (C / 32)) * 32, r0 = (rem / (C / 32)) * 32;
  int tx = tid & 31, ty = tid >> 5;
#pragma unroll
  for (int i = 0; i < 4; i++)
    t[ty + i * 8][tx] = f2bf(in[(size_t)(r0 + ty + i * 8) * C + c0 + tx]);
  __syncthreads();
#pragma unroll
  for (int i = 0; i < 4; i++)
    out[(size_t)(c0 + ty + i * 8) * R + r0 + tx] = t[tx][ty + i * 8];
}

// ---- LayerNorm (LN2): one wave per token, bf16 input -----------------------
__global__ __launch_bounds__(256) void ln_kernel(const u16* __restrict__ xin,
                                                 const float* __restrict__ g,
                                                 const float* __restrict__ b,
                                                 u16* __restrict__ out) {
  int wave = threadIdx.x >> 6, lane = threadIdx.x & 63;
  int token = blockIdx.x * 4 + wave;
  float v[12];
  const ushort4* xr = (const ushort4*)(xin + (size_t)token * DIM);
#pragma unroll
  for (int w = 0; w < 3; w++) {
    ushort4 q = xr[lane + w * 64];
    v[w * 4 + 0] = bf2f(q.x); v[w * 4 + 1] = bf2f(q.y);
    v[w * 4 + 2] = bf2f(q.z); v[w * 4 + 3] = bf2f(q.w);
  }
  float s = 0.f;
#pragma unroll
  for (int i = 0; i < 12; i++) s += v[i];
#pragma unroll
  for (int off = 32; off > 0; off >>= 1) s += __shfl_xor(s, off);
  float mu = s * (1.0f / DIM);
  float ss = 0.f;
#pragma unroll
  for (int i = 0; i < 12; i++) { float d = v[i] - mu; ss += d * d; }
#pragma unroll
  for (int off = 32; off > 0; off >>= 1) ss += __shfl_xor(ss, off);
  float rs = rsqrtf(ss * (1.0f / DIM) + 1e-5f);

  ushort4* orow = (ushort4*)(out + (size_t)token * DIM);
  const float4* g4 = (const float4*)g;
  const float4* b4 = (const float4*)b;
#pragma unroll
  for (int w = 0; w < 3; w++) {
    float4 gq = g4[lane + w * 64], bq = b4[lane + w * 64];
    ushort4 o;
    o.x = f2bf((v[w * 4 + 0] - mu) * rs * gq.x + bq.x);
    o.y = f2bf((v[w * 4 + 1] - mu) * rs * gq.y + bq.y);
    o.z = f2bf((v[w * 4 + 2] - mu) * rs * gq.z + bq.z);
    o.w = f2bf((v[w * 4 + 3] - mu) * rs * gq.w + bq.w);
    orow[lane + w * 64] = o;
  }
}

// ---- GEMM: C[M,N] = A[M,K] * BT[N,K]^T, bf16 in, fused epilogue ------------
// R13 structure: NP stacked BK=32 panels per stage round.
// R18: bank-conflict-free LDS via pre-swizzled global source (rule #21):
//   LDS physical (row, pc) holds logical k-chunk pc ^ ((row>>1)&3); frag
//   reads fetch logical chunk quad at pc = quad ^ ((c16>>1)&3).
// R27: DB template param. DB=0: original 2-barrier-per-round path.
//   DB=1 (proj/fc2): double-buffered LDS, ONE barrier per round; DMAs for
//   round r+1 issue right after the barrier and drain at round r+2's
//   barrier (full round in flight -> latency hidden). Mirrors attn v12.
// Flat grid, A-local XCD swizzle: by = b % (M/BM) (multiple of 8).
// EPI: 0 = qkv: Q/K cols bf16 store; V cols (>=1536) packed transposed store
//      1 = +bias(f32) + resid(f32) -> bf16 store (proj -> x1 trunk)
//      2 = +bias(f32), exact gelu -> bf16 store (fc1)
//      3 = +bias(f32) + resid(bf16) -> F32 store (fc2 -> d_out)
template <int BM, int BN, int EPI, int NP, int DB>
__global__ __launch_bounds__(256, 3) void gemm_bt(
    const u16* __restrict__ A, const u16* __restrict__ BT,
    void* __restrict__ Cout, const float* __restrict__ bias,
    const void* __restrict__ resid, int M, int N, int K,
    u16* __restrict__ vtb) {
  constexpr int MT = BM / 32, NT = BN / 32;        // mfma tiles per wave
  constexpr int ACH = BM / 16;                     // A 16-row chunks per panel
  constexpr int CPW = (BM + BN) / 64;              // chunks per wave per panel
  constexpr int NB = DB ? 2 : 1;                   // LDS buffers
  __shared__ __align__(16) u16 Alds[NB][NP][BM * 32];
  __shared__ __align__(16) u16 Blds[NB][NP][BN * 32];
  const int tid = threadIdx.x;
  const int lane = tid & 63, wave = tid >> 6;
  const int wr = wave >> 1, wc = wave & 1;
  const int nby = M / BM;                          // multiple of 8
  const int by = blockIdx.x % nby, bx = blockIdx.x / nby;
  const int bm = by * BM, bn = bx * BN;
  const int c16 = lane & 15, quad = lane >> 4;
  const int l4 = lane >> 2;
  // pre-swizzled source chunk: physical slot (row=l4, pc=lane&3) receives
  // logical k-chunk (lane&3) ^ ((l4>>1)&3)  [chunk*16 doesn't affect bits 1:2]
  const int lc = (((lane & 3) ^ ((l4 >> 1) & 3)) * 8);
  const int fsw = (c16 >> 1) & 3;                  // frag-read swizzle key

  f32x4 acc[MT][NT];
#pragma unroll
  for (int i = 0; i < MT; i++)
#pragma unroll
    for (int j = 0; j < NT; j++) acc[i][j] = (f32x4){0.f, 0.f, 0.f, 0.f};

  const u16* gsrc[CPW];
  u16* ldst[CPW];                      // dest in buffer 0, panel 0
  int hstep[CPW];                      // elems between panel p and p+1
  int bstep[CPW];                      // elems between buffer 0 and 1
#pragma unroll
  for (int c = 0; c < CPW; c++) {
    int chunk = wave * CPW + c;
    if (chunk < ACH) {
      gsrc[c] = A + (size_t)(bm + chunk * 16 + l4) * K + lc;
      ldst[c] = &Alds[0][0][0] + chunk * 512;
      hstep[c] = BM * 32;
      bstep[c] = NP * BM * 32;
    } else {
      int bc = chunk - ACH;
      gsrc[c] = BT + (size_t)(bn + bc * 16 + l4) * K + lc;
      ldst[c] = &Blds[0][0][0] + bc * 512;
      hstep[c] = BN * 32;
      bstep[c] = NP * BN * 32;
    }
  }

#define GB_STAGE(KK, BUF)                                                   \
  {                                                                         \
    _Pragma("unroll")                                                       \
    for (int c = 0; c < CPW; c++)                                           \
      _Pragma("unroll")                                                     \
      for (int p = 0; p < NP; p++)                                          \
        async_copy16(gsrc[c] + (KK) + 32 * p,                               \
                     ldst[c] + (BUF) * bstep[c] + p * hstep[c]);            \
  }
#define GB_COMPUTE(BUF)                                                     \
  {                                                                         \
    _Pragma("unroll")                                                       \
    for (int ks = 0; ks < NP; ks++) {                                       \
      short8 af[MT], bfr[NT];                                               \
      _Pragma("unroll")                                                     \
      for (int mt = 0; mt < MT; mt++)                                       \
        af[mt] = *(const short8*)(&Alds[BUF][ks][0] +                       \
                  (wr * (BM / 2) + mt * 16 + c16) * 32 + ((quad ^ fsw)) * 8); \
      _Pragma("unroll")                                                     \
      for (int nt = 0; nt < NT; nt++)                                       \
        bfr[nt] = *(const short8*)(&Blds[BUF][ks][0] +                      \
                  (wc * (BN / 2) + nt * 16 + c16) * 32 + ((quad ^ fsw)) * 8); \
      _Pragma("unroll")                                                     \
      for (int mt = 0; mt < MT; mt++)                                       \
        _Pragma("unroll")                                                   \
        for (int nt = 0; nt < NT; nt++)                                     \
          acc[mt][nt] = __builtin_amdgcn_mfma_f32_16x16x32_bf16(            \
              af[mt], bfr[nt], acc[mt][nt], 0, 0, 0);                       \
    }                                                                       \
  }

  if constexpr (DB == 0) {
    for (int kk = 0; kk < K; kk += 32 * NP) {
      __syncthreads();                  // prior round's frag reads done
      GB_STAGE(kk, 0);
      __syncthreads();                  // barrier drains vmcnt (LDS visible)
      GB_COMPUTE(0);
    }
  } else {
    GB_STAGE(0, 0);                     // prologue: round 0 -> buf 0
    const int nr = K / (32 * NP);
    for (int r = 0; r < nr; r++) {
      const int cb = r & 1;
      __syncthreads();                  // round-r DMAs (issued a full round
                                        // ago) drained + visible; all waves
                                        // done reading buf cb^1
      if (r + 1 < nr) GB_STAGE((r + 1) * 32 * NP, cb ^ 1);
      GB_COMPUTE(cb);
    }
  }
#undef GB_STAGE
#undef GB_COMPUTE

#pragma unroll
  for (int mt = 0; mt < MT; mt++) {
#pragma unroll
    for (int nt = 0; nt < NT; nt++) {
      int col = bn + wc * (BN / 2) + nt * 16 + c16;
      float bv = (EPI != 0) ? bias[col] : 0.f;
      int row0 = bm + wr * (BM / 2) + mt * 16 + quad * 4;
      if (EPI == 0 && col >= 2 * DIM) {
        // V columns: packed transposed store vt[(b*768+hd)][tok] (tok=row)
        int b = row0 >> 11;
        ushort4 pk;
        pk.x = f2bf(acc[mt][nt][0]); pk.y = f2bf(acc[mt][nt][1]);
        pk.z = f2bf(acc[mt][nt][2]); pk.w = f2bf(acc[mt][nt][3]);
        *(ushort4*)(vtb + ((size_t)b * DIM + col - 2 * DIM) * NSEQ + (row0 & 2047)) = pk;
        continue;
      }
#pragma unroll
      for (int r = 0; r < 4; r++) {
        int row = row0 + r;
        float vv = acc[mt][nt][r];
        if (EPI == 1) {
          vv += bv + ((const float*)resid)[(size_t)row * N + col];
          ((u16*)Cout)[(size_t)row * N + col] = f2bf(vv);
        } else if (EPI == 2) {
          vv += bv;
          vv = 0.5f * vv * (1.0f + erff(vv * 0.70710678118654752f));
          ((u16*)Cout)[(size_t)row * N + col] = f2bf(vv);
        } else if (EPI == 3) {
          vv += bv + bf2f(((const u16*)resid)[(size_t)row * N + col]);
          ((float*)Cout)[(size_t)row * N + col] = vv;     // f32 final output
        } else {
          ((u16*)Cout)[(size_t)row * N + col] = f2bf(vv);
        }
      }
    }
  }
}

// ---- flash attention v12r: split-K wave pairs + in-register P (cvt_pk) -----
// Grid/head-major XCD swizzle unchanged (24 | blocks). Block = 4 waves over a
// 64-row q-tile; wave (wq,wk): wq -> 32 q-rows, wk -> 32-key half of each
// 64-key tile. S^T = mfma(K,Q): lane (c16,quad) holds P[q=c16][kt*16+quad*4+r].
// PV A-frag needs P[q=c16][quad*8+j] -- a 4x4 transpose in the quad dim only:
// cvt_pk pairs to dwords, then 2x permlane32_swap + 2x permlane16_swap (VALU
// pipe, no LDS). Per-wave DS per iter: 4 K-frag + 4 V-frag b128 reads only.
// Partial O (32q x 64d) and L summed across the wk pair via LDS at the end.
__global__ __launch_bounds__(256, 3) void attn_kernel(const u16* __restrict__ qkv,
                                                      const u16* __restrict__ vt,
                                                      u16* __restrict__ o) {
  const int tid = threadIdx.x;
  const int lane = tid & 63, wave = tid >> 6;      // wave 0..3
  const int c16 = lane & 15, quad = lane >> 4;
  const int wq = wave >> 1, wk = wave & 1;         // q-half / key-half
  const int bh = blockIdx.x % (2 * NHEAD);         // head-major (XCD locality)
  const int qt = blockIdx.x / (2 * NHEAD);
  const int bb = bh / NHEAD, h = bh % NHEAD;
  __shared__ __align__(16) u16 Klds[2][64 * 64];   // [buf][key][d] swizzled
  __shared__ __align__(16) u16 Vtlds[2][64 * 64];  // [buf][d][key] swizzled
  const size_t base = (size_t)bb * NSEQ * QKV_N;
  const int q0 = qt * 64;
  const int sw = c16 & 7;                          // K/V chunk-swizzle key

  // Q frags (B-operand): lane holds Q[q0+wq*32+qs*16+c16][ch*32+quad*8+j]
  short8 qf[2][2];
#pragma unroll
  for (int qs = 0; qs < 2; qs++) {
    const u16* qp = qkv + base + (size_t)(q0 + wq * 32 + qs * 16 + c16) * QKV_N + h * HDIM;
    qf[qs][0] = *(const short8*)(qp + quad * 8);
    qf[qs][1] = *(const short8*)(qp + 32 + quad * 8);
  }

  float Ls[2] = {0.f, 0.f};
  f32x4 Of[2][4];
#pragma unroll
  for (int qs = 0; qs < 2; qs++)
#pragma unroll
    for (int dt = 0; dt < 4; dt++) Of[qs][dt] = (f32x4){0.f, 0.f, 0.f, 0.f};

  // staging: each wave stages 16 K-rows + 16 Vt-rows per tile (unchanged)
  const int srow = lane >> 3;
  const int schunk = (lane & 7) ^ srow;
  const int r0 = wave * 16;
  const u16* ksrc = qkv + base + (size_t)(r0 + srow) * QKV_N + DIM + h * HDIM + schunk * 8;
  const u16* vsrc = vt + ((size_t)bh * HDIM + r0 + srow) * NSEQ + schunk * 8;
  const float SC = 0.18033688011112042f;           // 0.125 * log2(e)

  // prologue: stage tile 0 into buffer 0
#pragma unroll
  for (int j = 0; j < 2; j++) {
    async_copy16(ksrc + (size_t)(8 * j) * QKV_N, Klds[0] + r0 * 64 + 8 * j * 64);
    async_copy16(vsrc + (size_t)(8 * j) * NSEQ, Vtlds[0] + r0 * 64 + 8 * j * 64);
  }

  for (int it = 0; it < NSEQ / 64; it++) {
    const int cur = it & 1;
    __syncthreads();   // drains DMA(it) + all waves done reading buf cur^1
    if (it + 1 < NSEQ / 64) {
      const int kt1 = (it + 1) * 64;
      u16* kd = Klds[cur ^ 1] + r0 * 64;
      u16* vd = Vtlds[cur ^ 1] + r0 * 64;
#pragma unroll
      for (int j = 0; j < 2; j++) {
        async_copy16(ksrc + (size_t)(kt1 + 8 * j) * QKV_N, kd + 8 * j * 64);
        async_copy16(vsrc + (size_t)(8 * j) * NSEQ + kt1, vd + 8 * j * 64);
      }
    }

    // K frags (A-operand): keys wk*32 + kt*16 + c16, this wave's half only
    short8 kf0[2], kf1[2];
#pragma unroll
    for (int kt = 0; kt < 2; kt++) {
      const u16* krow = Klds[cur] + (wk * 32 + kt * 16 + c16) * 64;
      kf0[kt] = *(const short8*)(krow + (quad ^ sw) * 8);
      kf1[kt] = *(const short8*)(krow + ((quad + 4) ^ sw) * 8);
    }

    // S^T[key][q]: row = key local (kt*16+quad*4+r), col = q (c16)
    f32x4 St[2][2];
#pragma unroll
    for (int qs = 0; qs < 2; qs++)
#pragma unroll
      for (int kt = 0; kt < 2; kt++) {
        f32x4 s = (f32x4){0.f, 0.f, 0.f, 0.f};
        s = __builtin_amdgcn_mfma_f32_16x16x32_bf16(kf0[kt], qf[qs][0], s, 0, 0, 0);
        s = __builtin_amdgcn_mfma_f32_16x16x32_bf16(kf1[kt], qf[qs][1], s, 0, 0, 0);
        St[qs][kt] = s;
      }

    // V frags early (independent of softmax): keys wk*32 + quad*8 + j
    short8 vf[4];
#pragma unroll
    for (int dt = 0; dt < 4; dt++) {
      const u16* vrow = Vtlds[cur] + (dt * 16 + c16) * 64;
      vf[dt] = *(const short8*)(vrow + ((wk * 4 + quad) ^ sw) * 8);
    }

    // softmax + in-register P->A-frag transpose (quad dim only):
    //   pl32swap: a<->b across lane halves; pl16swap: odd<->even 16-rows
    //   result dwords: D0=a0, D1=a1, D2=b0, D3=b1 = keys {8q..8q+7} of row c16
    short8 pf[2];
#pragma unroll
    for (int qs = 0; qs < 2; qs++) {
      float p[2][4];
#pragma unroll
      for (int kt = 0; kt < 2; kt++)
#pragma unroll
        for (int r = 0; r < 4; r++)
          p[kt][r] = __builtin_amdgcn_exp2f(St[qs][kt][r] * SC);
      Ls[qs] += ((p[0][0] + p[0][1]) + (p[0][2] + p[0][3])) +
                ((p[1][0] + p[1][1]) + (p[1][2] + p[1][3]));
      unsigned a0 = cvt_pk_bf16(p[0][0], p[0][1]);
      unsigned a1 = cvt_pk_bf16(p[0][2], p[0][3]);
      unsigned b0 = cvt_pk_bf16(p[1][0], p[1][1]);
      unsigned b1 = cvt_pk_bf16(p[1][2], p[1][3]);
      pl32swap(a0, b0);
      pl32swap(a1, b1);
      pl16swap(a0, b0);
      pl16swap(a1, b1);
      union { unsigned u[4]; short8 s; } pk_;
      pk_.u[0] = a0; pk_.u[1] = a1; pk_.u[2] = b0; pk_.u[3] = b1;
      pf[qs] = pk_.s;
    }

    // PV: A = P[16q x 32keys local], B^T = Vt[d][key] frags
#pragma unroll
    for (int dt = 0; dt < 4; dt++)
#pragma unroll
      for (int qs = 0; qs < 2; qs++)
        Of[qs][dt] = __builtin_amdgcn_mfma_f32_16x16x32_bf16(pf[qs], vf[dt],
                                                             Of[qs][dt], 0, 0, 0);
  }

  // ---- cross-wave (wk) reduction of O,L; normalize + store (wk==0) ---------
  __syncthreads();                     // all waves done with K/V LDS reads
  float* red = (float*)&Klds[0][0];    // 16 KB: wk==1 waves' partial O
  float* lred = (float*)&Vtlds[0][0];  // 1 KB: wk==1 waves' partial L
  if (wk == 1) {
    float* dst = red + wq * 2048;
#pragma unroll
    for (int qs = 0; qs < 2; qs++)
#pragma unroll
      for (int dt = 0; dt < 4; dt++)
        *(f32x4*)(dst + (qs * 4 + dt) * 256 + lane * 4) = Of[qs][dt];
    lred[wq * 128 + lane] = Ls[0];
    lred[wq * 128 + 64 + lane] = Ls[1];
  }
  __syncthreads();
  if (wk == 0) {
    const float* src = red + wq * 2048;
#pragma unroll
    for (int qs = 0; qs < 2; qs++)
#pragma unroll
      for (int dt = 0; dt < 4; dt++)
        Of[qs][dt] += *(const f32x4*)(src + (qs * 4 + dt) * 256 + lane * 4);
    float t0 = Ls[0] + lred[wq * 128 + lane];
    float t1 = Ls[1] + lred[wq * 128 + 64 + lane];
    // row totals: sum the 4 quad-partials (keys split across quads)
    t0 += __shfl_xor(t0, 16); t0 += __shfl_xor(t0, 32);
    t1 += __shfl_xor(t1, 16); t1 += __shfl_xor(t1, 32);
#pragma unroll
    for (int qs = 0; qs < 2; qs++) {
      float tq = qs ? t1 : t0;
#pragma unroll
      for (int r = 0; r < 4; r++) {
        float L = __shfl(tq, quad * 4 + r);    // row total lives at lane c16=row
        int token = q0 + wq * 32 + qs * 16 + quad * 4 + r;
        u16* orow = o + (size_t)(bb * NSEQ + token) * DIM + h * HDIM;
#pragma unroll
        for (int dt = 0; dt < 4; dt++)
          orow[dt * 16 + c16] = f2bf(Of[qs][dt][r] / L);
      }
    }
  }
}

// ---------------------------------------------------------------------------
extern "C" void kernel_launch(void* const* d_in, const int* in_sizes, int n_in,
                              void* d_out, int out_size, void* d_ws, size_t ws_size,
                              hipStream_t stream) {
  (void)in_sizes; (void)n_in; (void)out_size; (void)ws_size;
  const float* x      = (const float*)d_in[0];
  const float* ln1_g  = (const float*)d_in[1];
  const float* ln1_b  = (const float*)d_in[2];
  const float* w_qkv  = (const float*)d_in[3];
  const float* w_proj = (const float*)d_in[4];
  const float* b_proj = (const float*)d_in[5];
  const float* ln2_g  = (const float*)d_in[6];
  const float* ln2_b  = (const float*)d_in[7];
  const float* w_fc1  = (const float*)d_in[8];
  const float* b_fc1  = (const float*)d_in[9];
  const float* w_fc2  = (const float*)d_in[10];
  const float* b_fc2  = (const float*)d_in[11];
  float* out = (float*)d_out;   // f32 output (reference dtype)

  // ---- workspace layout: ~55.8 MiB total ----
  char* p = (char*)d_ws;
  u16* h_bf   = (u16*)p; p += (size_t)TOKENS * DIM * 2;     //  h, then h2
  u16* qkv_bf = (u16*)p; p += (size_t)TOKENS * QKV_N * 2;
  u16* o_bf   = (u16*)p; p += (size_t)TOKENS * DIM * 2;
  u16* x1_bf  = (u16*)p; p += (size_t)TOKENS * DIM * 2;     //  trunk
  u16* wprojT = (u16*)p; p += (size_t)DIM * DIM * 2;
  u16* wfc1T  = (u16*)p; p += (size_t)HID * DIM * 2;
  u16* wfc2T  = (u16*)p; p += (size_t)DIM * HID * 2;
  u16* wqkvT  = (u16*)p; p += (size_t)QKV_N * DIM * 2;
  u16* vtb    = (u16*)p; p += (size_t)TOKENS * DIM * 2;     //  V transposed
  u16* m_bf   = qkv_bf;  // fc1 out [4096,3072] overlays dead [qkv|o] exactly

  prep_kernel<<<dim3(1024 + 6912), 256, 0, stream>>>(
      x, ln1_g, ln1_b, h_bf,
      w_qkv, wqkvT, w_proj, wprojT, w_fc1, wfc1T, w_fc2, wfc2T);

  gemm_bt<64, 128, 0, 2, 0><<<dim3((QKV_N / 128) * (TOKENS / 64)), 256, 0, stream>>>(
      h_bf, wqkvT, qkv_bf, nullptr, nullptr, TOKENS, QKV_N, DIM, vtb);
  attn_kernel<<<dim3(2 * NHEAD * (NSEQ / 64)), 256, 0, stream>>>(qkv_bf, vtb, o_bf);
  gemm_bt<64, 64, 1, 2, 1><<<dim3((DIM / 64) * (TOKENS / 64)), 256, 0, stream>>>(
      o_bf, wprojT, x1_bf, b_proj, x, TOKENS, DIM, DIM, nullptr);
  ln_kernel<<<TOKENS / 4, 256, 0, stream>>>(x1_bf, ln2_g, ln2_b, h_bf);
  gemm_bt<64, 128, 2, 2, 0><<<dim3((HID / 128) * (TOKENS / 64)), 256, 0, stream>>>(
      h_bf, wfc1T, m_bf, b_fc1, nullptr, TOKENS, HID, DIM, nullptr);
  gemm_bt<64, 64, 3, 2, 1><<<dim3((DIM / 64) * (TOKENS / 64)), 256, 0, stream>>>(
      m_bf, wfc2T, out, b_fc2, x1_bf, TOKENS, DIM, HID, nullptr);
}

// Round 14
// 240.005 us; speedup vs baseline: 1.0607x; 1.0033x over previous
//
#include <hip/hip_runtime.h>
#include <math.h>

// ---------------------------------------------------------------------------
// Transformer block (pre-LN). f32 in / f32 out (bf16-space comparison).
// Compute: bf16 MFMA, f32 accum. Workspace ~55.8 MiB.
// R29: pure revert to R27 (240.8us verified). R28 post-mortem: switching
//      qkv/fc1 to <NP=1,DB=1> corrupted output (absmax 8e32); defect not
//      localizable by inspection. DO NOT retry NP=1+DB=1 (BN=128) without
//      isolated single-kernel debugging. Known-good config: qkv/fc1
//      <NP=2,DB=0>; proj/fc2 <NP=2,DB=1> (R27 win, 246.5->240.8);
//      attn v12r frozen (43.4us, absmax 0.03125).
// MFMA layouts (guide m89/m91/m92/m120):
//   A-frag:  A[m=lane&15][k=quad*8+j]
//   B-frag:  BT[n=lane&15][k=quad*8+j]
//   C/D:     row = quad*4 + reg, col = lane&15
// ---------------------------------------------------------------------------

typedef unsigned short u16;
typedef __attribute__((ext_vector_type(8))) short short8;   // 8 x bf16
typedef __attribute__((ext_vector_type(4))) float f32x4;

#define TOKENS 4096
#define DIM    768
#define QKV_N  2304
#define HID    3072
#define NSEQ   2048
#define NHEAD  12
#define HDIM   64

__device__ __forceinline__ float bf2f(u16 u) {
  union { unsigned i; float f; } v; v.i = ((unsigned)u) << 16; return v.f;
}
__device__ __forceinline__ u16 f2bf(float f) {
  union { float f; unsigned i; } v; v.f = f;
  unsigned r = v.i + 0x7fffu + ((v.i >> 16) & 1u);   // RNE
  return (u16)(r >> 16);
}
// v_cvt_pk_bf16_f32: dst.lo = bf16(lo), dst.hi = bf16(hi), RNE
__device__ __forceinline__ unsigned cvt_pk_bf16(float lo, float hi) {
  unsigned r;
  asm("v_cvt_pk_bf16_f32 %0, %1, %2" : "=v"(r) : "v"(lo), "v"(hi));
  return r;
}
// v_permlane32_swap_b32: a[32:63] <-> b[0:31]
__device__ __forceinline__ void pl32swap(unsigned &a, unsigned &b) {
  asm("v_permlane32_swap_b32 %0, %1" : "+v"(a), "+v"(b));
}
// v_permlane16_swap_b32: a's odd 16-rows <-> b's even 16-rows
__device__ __forceinline__ void pl16swap(unsigned &a, unsigned &b) {
  asm("v_permlane16_swap_b32 %0, %1" : "+v"(a), "+v"(b));
}

// async global->LDS, 16B/lane. LDS dest = wave-uniform base + lane*16 (m104).
__device__ __forceinline__ void async_copy16(const u16* g, u16* l) {
  __builtin_amdgcn_global_load_lds(
      (const __attribute__((address_space(1))) unsigned int*)(unsigned long long)g,
      (__attribute__((address_space(3))) unsigned int*)(unsigned int)(unsigned long long)l,
      16, 0, 0);
}

// ---- prep: 4 weight transposes + LN1, one dispatch --------------------------
// blocks 0..1023: LN1 (4 tokens each). blocks 1024..7935: 32x32 transposes.
__global__ __launch_bounds__(256) void prep_kernel(
    const float* __restrict__ x, const float* __restrict__ g,
    const float* __restrict__ b, u16* __restrict__ h,
    const float* __restrict__ in0, u16* __restrict__ out0,   // 768x2304
    const float* __restrict__ in1, u16* __restrict__ out1,   // 768x768
    const float* __restrict__ in2, u16* __restrict__ out2,   // 768x3072
    const float* __restrict__ in3, u16* __restrict__ out3) { // 3072x768
  const int tid = threadIdx.x;
  if (blockIdx.x < 1024) {
    // ---- LN1: one wave per token, f32 input ----
    int wave = tid >> 6, lane = tid & 63;
    int token = blockIdx.x * 4 + wave;
    float v[12];
    const float4* xr = (const float4*)(x + (size_t)token * DIM);
#pragma unroll
    for (int w = 0; w < 3; w++) {
      float4 q = xr[lane + w * 64];
      v[w * 4 + 0] = q.x; v[w * 4 + 1] = q.y; v[w * 4 + 2] = q.z; v[w * 4 + 3] = q.w;
    }
    float s = 0.f;
#pragma unroll
    for (int i = 0; i < 12; i++) s += v[i];
#pragma unroll
    for (int off = 32; off > 0; off >>= 1) s += __shfl_xor(s, off);
    float mu = s * (1.0f / DIM);
    float ss = 0.f;
#pragma unroll
    for (int i = 0; i < 12; i++) { float d = v[i] - mu; ss += d * d; }
#pragma unroll
    for (int off = 32; off > 0; off >>= 1) ss += __shfl_xor(ss, off);
    float rs = rsqrtf(ss * (1.0f / DIM) + 1e-5f);
    ushort4* orow = (ushort4*)(h + (size_t)token * DIM);
    const float4* g4 = (const float4*)g;
    const float4* b4 = (const float4*)b;
#pragma unroll
    for (int w = 0; w < 3; w++) {
      float4 gq = g4[lane + w * 64], bq = b4[lane + w * 64];
      ushort4 o;
      o.x = f2bf((v[w * 4 + 0] - mu) * rs * gq.x + bq.x);
      o.y = f2bf((v[w * 4 + 1] - mu) * rs * gq.y + bq.y);
      o.z = f2bf((v[w * 4 + 2] - mu) * rs * gq.z + bq.z);
      o.w = f2bf((v[w * 4 + 3] - mu) * rs * gq.w + bq.w);
      orow[lane + w * 64] = o;
    }
    return;
  }
  // ---- weight transpose ----
  __shared__ u16 t[32][33];
  int bid = blockIdx.x - 1024, rem;
  const float* in; u16* out; int R, C;
  if (bid < 1728)      { in = in0; out = out0; R = 768;  C = 2304; rem = bid; }
  else if (bid < 2304) { in = in1; out = out1; R = 768;  C = 768;  rem = bid - 1728; }
  else if (bid < 4608) { in = in2; out = out2; R = 768;  C = 3072; rem = bid - 2304; }
  else                 { in = in3; out = out3; R = 3072; C = 768;  rem = bid - 4608; }
  int c0 = (rem % (C / 32)) * 32, r0 = (rem / (C / 32)) * 32;
  int tx = tid & 31, ty = tid >> 5;
#pragma unroll
  for (int i = 0; i < 4; i++)
    t[ty + i * 8][tx] = f2bf(in[(size_t)(r0 + ty + i * 8) * C + c0 + tx]);
  __syncthreads();
#pragma unroll
  for (int i = 0; i < 4; i++)
    out[(size_t)(c0 + ty + i * 8) * R + r0 + tx] = t[tx][ty + i * 8];
}

// ---- LayerNorm (LN2): one wave per token, bf16 input -----------------------
__global__ __launch_bounds__(256) void ln_kernel(const u16* __restrict__ xin,
                                                 const float* __restrict__ g,
                                                 const float* __restrict__ b,
                                                 u16* __restrict__ out) {
  int wave = threadIdx.x >> 6, lane = threadIdx.x & 63;
  int token = blockIdx.x * 4 + wave;
  float v[12];
  const ushort4* xr = (const ushort4*)(xin + (size_t)token * DIM);
#pragma unroll
  for (int w = 0; w < 3; w++) {
    ushort4 q = xr[lane + w * 64];
    v[w * 4 + 0] = bf2f(q.x); v[w * 4 + 1] = bf2f(q.y);
    v[w * 4 + 2] = bf2f(q.z); v[w * 4 + 3] = bf2f(q.w);
  }
  float s = 0.f;
#pragma unroll
  for (int i = 0; i < 12; i++) s += v[i];
#pragma unroll
  for (int off = 32; off > 0; off >>= 1) s += __shfl_xor(s, off);
  float mu = s * (1.0f / DIM);
  float ss = 0.f;
#pragma unroll
  for (int i = 0; i < 12; i++) { float d = v[i] - mu; ss += d * d; }
#pragma unroll
  for (int off = 32; off > 0; off >>= 1) ss += __shfl_xor(ss, off);
  float rs = rsqrtf(ss * (1.0f / DIM) + 1e-5f);

  ushort4* orow = (ushort4*)(out + (size_t)token * DIM);
  const float4* g4 = (const float4*)g;
  const float4* b4 = (const float4*)b;
#pragma unroll
  for (int w = 0; w < 3; w++) {
    float4 gq = g4[lane + w * 64], bq = b4[lane + w * 64];
    ushort4 o;
    o.x = f2bf((v[w * 4 + 0] - mu) * rs * gq.x + bq.x);
    o.y = f2bf((v[w * 4 + 1] - mu) * rs * gq.y + bq.y);
    o.z = f2bf((v[w * 4 + 2] - mu) * rs * gq.z + bq.z);
    o.w = f2bf((v[w * 4 + 3] - mu) * rs * gq.w + bq.w);
    orow[lane + w * 64] = o;
  }
}

// ---- GEMM: C[M,N] = A[M,K] * BT[N,K]^T, bf16 in, fused epilogue ------------
// R13 structure: NP stacked BK=32 panels per stage round.
// R18: bank-conflict-free LDS via pre-swizzled global source (rule #21):
//   LDS physical (row, pc) holds logical k-chunk pc ^ ((row>>1)&3); frag
//   reads fetch logical chunk quad at pc = quad ^ ((c16>>1)&3).
// R27: DB template param. DB=0: original 2-barrier-per-round path.
//   DB=1 (proj/fc2): double-buffered LDS, ONE barrier per round; DMAs for
//   round r+1 issue right after the barrier and drain at round r+2's
//   barrier (full round in flight -> latency hidden). Mirrors attn v12.
//   R28 NOTE: <NP=1,DB=1> with BN=128 corrupted output -- unexplained; do
//   not use without isolated debugging. Validated: <NP=2,DB=1> BN=64.
// Flat grid, A-local XCD swizzle: by = b % (M/BM) (multiple of 8).
// EPI: 0 = qkv: Q/K cols bf16 store; V cols (>=1536) packed transposed store
//      1 = +bias(f32) + resid(f32) -> bf16 store (proj -> x1 trunk)
//      2 = +bias(f32), exact gelu -> bf16 store (fc1)
//      3 = +bias(f32) + resid(bf16) -> F32 store (fc2 -> d_out)
template <int BM, int BN, int EPI, int NP, int DB>
__global__ __launch_bounds__(256, 3) void gemm_bt(
    const u16* __restrict__ A, const u16* __restrict__ BT,
    void* __restrict__ Cout, const float* __restrict__ bias,
    const void* __restrict__ resid, int M, int N, int K,
    u16* __restrict__ vtb) {
  constexpr int MT = BM / 32, NT = BN / 32;        // mfma tiles per wave
  constexpr int ACH = BM / 16;                     // A 16-row chunks per panel
  constexpr int CPW = (BM + BN) / 64;              // chunks per wave per panel
  constexpr int NB = DB ? 2 : 1;                   // LDS buffers
  __shared__ __align__(16) u16 Alds[NB][NP][BM * 32];
  __shared__ __align__(16) u16 Blds[NB][NP][BN * 32];
  const int tid = threadIdx.x;
  const int lane = tid & 63, wave = tid >> 6;
  const int wr = wave >> 1, wc = wave & 1;
  const int nby = M / BM;                          // multiple of 8
  const int by = blockIdx.x % nby, bx = blockIdx.x / nby;
  const int bm = by * BM, bn = bx * BN;
  const int c16 = lane & 15, quad = lane >> 4;
  const int l4 = lane >> 2;
  // pre-swizzled source chunk: physical slot (row=l4, pc=lane&3) receives
  // logical k-chunk (lane&3) ^ ((l4>>1)&3)  [chunk*16 doesn't affect bits 1:2]
  const int lc = (((lane & 3) ^ ((l4 >> 1) & 3)) * 8);
  const int fsw = (c16 >> 1) & 3;                  // frag-read swizzle key

  f32x4 acc[MT][NT];
#pragma unroll
  for (int i = 0; i < MT; i++)
#pragma unroll
    for (int j = 0; j < NT; j++) acc[i][j] = (f32x4){0.f, 0.f, 0.f, 0.f};

  const u16* gsrc[CPW];
  u16* ldst[CPW];                      // dest in buffer 0, panel 0
  int hstep[CPW];                      // elems between panel p and p+1
  int bstep[CPW];                      // elems between buffer 0 and 1
#pragma unroll
  for (int c = 0; c < CPW; c++) {
    int chunk = wave * CPW + c;
    if (chunk < ACH) {
      gsrc[c] = A + (size_t)(bm + chunk * 16 + l4) * K + lc;
      ldst[c] = &Alds[0][0][0] + chunk * 512;
      hstep[c] = BM * 32;
      bstep[c] = NP * BM * 32;
    } else {
      int bc = chunk - ACH;
      gsrc[c] = BT + (size_t)(bn + bc * 16 + l4) * K + lc;
      ldst[c] = &Blds[0][0][0] + bc * 512;
      hstep[c] = BN * 32;
      bstep[c] = NP * BN * 32;
    }
  }

#define GB_STAGE(KK, BUF)                                                   \
  {                                                                         \
    _Pragma("unroll")                                                       \
    for (int c = 0; c < CPW; c++)                                           \
      _Pragma("unroll")                                                     \
      for (int p = 0; p < NP; p++)                                          \
        async_copy16(gsrc[c] + (KK) + 32 * p,                               \
                     ldst[c] + (BUF) * bstep[c] + p * hstep[c]);            \
  }
#define GB_COMPUTE(BUF)                                                     \
  {                                                                         \
    _Pragma("unroll")                                                       \
    for (int ks = 0; ks < NP; ks++) {                                       \
      short8 af[MT], bfr[NT];                                               \
      _Pragma("unroll")                                                     \
      for (int mt = 0; mt < MT; mt++)                                       \
        af[mt] = *(const short8*)(&Alds[BUF][ks][0] +                       \
                  (wr * (BM / 2) + mt * 16 + c16) * 32 + ((quad ^ fsw)) * 8); \
      _Pragma("unroll")                                                     \
      for (int nt = 0; nt < NT; nt++)                                       \
        bfr[nt] = *(const short8*)(&Blds[BUF][ks][0] +                      \
                  (wc * (BN / 2) + nt * 16 + c16) * 32 + ((quad ^ fsw)) * 8); \
      _Pragma("unroll")                                                     \
      for (int mt = 0; mt < MT; mt++)                                       \
        _Pragma("unroll")                                                   \
        for (int nt = 0; nt < NT; nt++)                                     \
          acc[mt][nt] = __builtin_amdgcn_mfma_f32_16x16x32_bf16(            \
              af[mt], bfr[nt], acc[mt][nt], 0, 0, 0);                       \
    }                                                                       \
  }

  if constexpr (DB == 0) {
    for (int kk = 0; kk < K; kk += 32 * NP) {
      __syncthreads();                  // prior round's frag reads done
      GB_STAGE(kk, 0);
      __syncthreads();                  // barrier drains vmcnt (LDS visible)
      GB_COMPUTE(0);
    }
  } else {
    GB_STAGE(0, 0);                     // prologue: round 0 -> buf 0
    const int nr = K / (32 * NP);
    for (int r = 0; r < nr; r++) {
      const int cb = r & 1;
      __syncthreads();                  // round-r DMAs (issued a full round
                                        // ago) drained + visible; all waves
                                        // done reading buf cb^1
      if (r + 1 < nr) GB_STAGE((r + 1) * 32 * NP, cb ^ 1);
      GB_COMPUTE(cb);
    }
  }
#undef GB_STAGE
#undef GB_COMPUTE

#pragma unroll
  for (int mt = 0; mt < MT; mt++) {
#pragma unroll
    for (int nt = 0; nt < NT; nt++) {
      int col = bn + wc * (BN / 2) + nt * 16 + c16;
      float bv = (EPI != 0) ? bias[col] : 0.f;
      int row0 = bm + wr * (BM / 2) + mt * 16 + quad * 4;
      if (EPI == 0 && col >= 2 * DIM) {
        // V columns: packed transposed store vt[(b*768+hd)][tok] (tok=row)
        int b = row0 >> 11;
        ushort4 pk;
        pk.x = f2bf(acc[mt][nt][0]); pk.y = f2bf(acc[mt][nt][1]);
        pk.z = f2bf(acc[mt][nt][2]); pk.w = f2bf(acc[mt][nt][3]);
        *(ushort4*)(vtb + ((size_t)b * DIM + col - 2 * DIM) * NSEQ + (row0 & 2047)) = pk;
        continue;
      }
#pragma unroll
      for (int r = 0; r < 4; r++) {
        int row = row0 + r;
        float vv = acc[mt][nt][r];
        if (EPI == 1) {
          vv += bv + ((const float*)resid)[(size_t)row * N + col];
          ((u16*)Cout)[(size_t)row * N + col] = f2bf(vv);
        } else if (EPI == 2) {
          vv += bv;
          vv = 0.5f * vv * (1.0f + erff(vv * 0.70710678118654752f));
          ((u16*)Cout)[(size_t)row * N + col] = f2bf(vv);
        } else if (EPI == 3) {
          vv += bv + bf2f(((const u16*)resid)[(size_t)row * N + col]);
          ((float*)Cout)[(size_t)row * N + col] = vv;     // f32 final output
        } else {
          ((u16*)Cout)[(size_t)row * N + col] = f2bf(vv);
        }
      }
    }
  }
}

// ---- flash attention v12r: split-K wave pairs + in-register P (cvt_pk) -----
// Grid/head-major XCD swizzle unchanged (24 | blocks). Block = 4 waves over a
// 64-row q-tile; wave (wq,wk): wq -> 32 q-rows, wk -> 32-key half of each
// 64-key tile. S^T = mfma(K,Q): lane (c16,quad) holds P[q=c16][kt*16+quad*4+r].
// PV A-frag needs P[q=c16][quad*8+j] -- a 4x4 transpose in the quad dim only:
// cvt_pk pairs to dwords, then 2x permlane32_swap + 2x permlane16_swap (VALU
// pipe, no LDS). Per-wave DS per iter: 4 K-frag + 4 V-frag b128 reads only.
// Partial O (32q x 64d) and L summed across the wk pair via LDS at the end.
__global__ __launch_bounds__(256, 3) void attn_kernel(const u16* __restrict__ qkv,
                                                      const u16* __restrict__ vt,
                                                      u16* __restrict__ o) {
  const int tid = threadIdx.x;
  const int lane = tid & 63, wave = tid >> 6;      // wave 0..3
  const int c16 = lane & 15, quad = lane >> 4;
  const int wq = wave >> 1, wk = wave & 1;         // q-half / key-half
  const int bh = blockIdx.x % (2 * NHEAD);         // head-major (XCD locality)
  const int qt = blockIdx.x / (2 * NHEAD);
  const int bb = bh / NHEAD, h = bh % NHEAD;
  __shared__ __align__(16) u16 Klds[2][64 * 64];   // [buf][key][d] swizzled
  __shared__ __align__(16) u16 Vtlds[2][64 * 64];  // [buf][d][key] swizzled
  const size_t base = (size_t)bb * NSEQ * QKV_N;
  const int q0 = qt * 64;
  const int sw = c16 & 7;                          // K/V chunk-swizzle key

  // Q frags (B-operand): lane holds Q[q0+wq*32+qs*16+c16][ch*32+quad*8+j]
  short8 qf[2][2];
#pragma unroll
  for (int qs = 0; qs < 2; qs++) {
    const u16* qp = qkv + base + (size_t)(q0 + wq * 32 + qs * 16 + c16) * QKV_N + h * HDIM;
    qf[qs][0] = *(const short8*)(qp + quad * 8);
    qf[qs][1] = *(const short8*)(qp + 32 + quad * 8);
  }

  float Ls[2] = {0.f, 0.f};
  f32x4 Of[2][4];
#pragma unroll
  for (int qs = 0; qs < 2; qs++)
#pragma unroll
    for (int dt = 0; dt < 4; dt++) Of[qs][dt] = (f32x4){0.f, 0.f, 0.f, 0.f};

  // staging: each wave stages 16 K-rows + 16 Vt-rows per tile (unchanged)
  const int srow = lane >> 3;
  const int schunk = (lane & 7) ^ srow;
  const int r0 = wave * 16;
  const u16* ksrc = qkv + base + (size_t)(r0 + srow) * QKV_N + DIM + h * HDIM + schunk * 8;
  const u16* vsrc = vt + ((size_t)bh * HDIM + r0 + srow) * NSEQ + schunk * 8;
  const float SC = 0.18033688011112042f;           // 0.125 * log2(e)

  // prologue: stage tile 0 into buffer 0
#pragma unroll
  for (int j = 0; j < 2; j++) {
    async_copy16(ksrc + (size_t)(8 * j) * QKV_N, Klds[0] + r0 * 64 + 8 * j * 64);
    async_copy16(vsrc + (size_t)(8 * j) * NSEQ, Vtlds[0] + r0 * 64 + 8 * j * 64);
  }

  for (int it = 0; it < NSEQ / 64; it++) {
    const int cur = it & 1;
    __syncthreads();   // drains DMA(it) + all waves done reading buf cur^1
    if (it + 1 < NSEQ / 64) {
      const int kt1 = (it + 1) * 64;
      u16* kd = Klds[cur ^ 1] + r0 * 64;
      u16* vd = Vtlds[cur ^ 1] + r0 * 64;
#pragma unroll
      for (int j = 0; j < 2; j++) {
        async_copy16(ksrc + (size_t)(kt1 + 8 * j) * QKV_N, kd + 8 * j * 64);
        async_copy16(vsrc + (size_t)(8 * j) * NSEQ + kt1, vd + 8 * j * 64);
      }
    }

    // K frags (A-operand): keys wk*32 + kt*16 + c16, this wave's half only
    short8 kf0[2], kf1[2];
#pragma unroll
    for (int kt = 0; kt < 2; kt++) {
      const u16* krow = Klds[cur] + (wk * 32 + kt * 16 + c16) * 64;
      kf0[kt] = *(const short8*)(krow + (quad ^ sw) * 8);
      kf1[kt] = *(const short8*)(krow + ((quad + 4) ^ sw) * 8);
    }

    // S^T[key][q]: row = key local (kt*16+quad*4+r), col = q (c16)
    f32x4 St[2][2];
#pragma unroll
    for (int qs = 0; qs < 2; qs++)
#pragma unroll
      for (int kt = 0; kt < 2; kt++) {
        f32x4 s = (f32x4){0.f, 0.f, 0.f, 0.f};
        s = __builtin_amdgcn_mfma_f32_16x16x32_bf16(kf0[kt], qf[qs][0], s, 0, 0, 0);
        s = __builtin_amdgcn_mfma_f32_16x16x32_bf16(kf1[kt], qf[qs][1], s, 0, 0, 0);
        St[qs][kt] = s;
      }

    // V frags early (independent of softmax): keys wk*32 + quad*8 + j
    short8 vf[4];
#pragma unroll
    for (int dt = 0; dt < 4; dt++) {
      const u16* vrow = Vtlds[cur] + (dt * 16 + c16) * 64;
      vf[dt] = *(const short8*)(vrow + ((wk * 4 + quad) ^ sw) * 8);
    }

    // softmax + in-register P->A-frag transpose (quad dim only):
    //   pl32swap: a<->b across lane halves; pl16swap: odd<->even 16-rows
    //   result dwords: D0=a0, D1=a1, D2=b0, D3=b1 = keys {8q..8q+7} of row c16
    short8 pf[2];
#pragma unroll
    for (int qs = 0; qs < 2; qs++) {
      float p[2][4];
#pragma unroll
      for (int kt = 0; kt < 2; kt++)
#pragma unroll
        for (int r = 0; r < 4; r++)
          p[kt][r] = __builtin_amdgcn_exp2f(St[qs][kt][r] * SC);
      Ls[qs] += ((p[0][0] + p[0][1]) + (p[0][2] + p[0][3])) +
                ((p[1][0] + p[1][1]) + (p[1][2] + p[1][3]));
      unsigned a0 = cvt_pk_bf16(p[0][0], p[0][1]);
      unsigned a1 = cvt_pk_bf16(p[0][2], p[0][3]);
      unsigned b0 = cvt_pk_bf16(p[1][0], p[1][1]);
      unsigned b1 = cvt_pk_bf16(p[1][2], p[1][3]);
      pl32swap(a0, b0);
      pl32swap(a1, b1);
      pl16swap(a0, b0);
      pl16swap(a1, b1);
      union { unsigned u[4]; short8 s; } pk_;
      pk_.u[0] = a0; pk_.u[1] = a1; pk_.u[2] = b0; pk_.u[3] = b1;
      pf[qs] = pk_.s;
    }

    // PV: A = P[16q x 32keys local], B^T = Vt[d][key] frags
#pragma unroll
    for (int dt = 0; dt < 4; dt++)
#pragma unroll
      for (int qs = 0; qs < 2; qs++)
        Of[qs][dt] = __builtin_amdgcn_mfma_f32_16x16x32_bf16(pf[qs], vf[dt],
                                                             Of[qs][dt], 0, 0, 0);
  }

  // ---- cross-wave (wk) reduction of O,L; normalize + store (wk==0) ---------
  __syncthreads();                     // all waves done with K/V LDS reads
  float* red = (float*)&Klds[0][0];    // 16 KB: wk==1 waves' partial O
  float* lred = (float*)&Vtlds[0][0];  // 1 KB: wk==1 waves' partial L
  if (wk == 1) {
    float* dst = red + wq * 2048;
#pragma unroll
    for (int qs = 0; qs < 2; qs++)
#pragma unroll
      for (int dt = 0; dt < 4; dt++)
        *(f32x4*)(dst + (qs * 4 + dt) * 256 + lane * 4) = Of[qs][dt];
    lred[wq * 128 + lane] = Ls[0];
    lred[wq * 128 + 64 + lane] = Ls[1];
  }
  __syncthreads();
  if (wk == 0) {
    const float* src = red + wq * 2048;
#pragma unroll
    for (int qs = 0; qs < 2; qs++)
#pragma unroll
      for (int dt = 0; dt < 4; dt++)
        Of[qs][dt] += *(const f32x4*)(src + (qs * 4 + dt) * 256 + lane * 4);
    float t0 = Ls[0] + lred[wq * 128 + lane];
    float t1 = Ls[1] + lred[wq * 128 + 64 + lane];
    // row totals: sum the 4 quad-partials (keys split across quads)
    t0 += __shfl_xor(t0, 16); t0 += __shfl_xor(t0, 32);
    t1 += __shfl_xor(t1, 16); t1 += __shfl_xor(t1, 32);
#pragma unroll
    for (int qs = 0; qs < 2; qs++) {
      float tq = qs ? t1 : t0;
#pragma unroll
      for (int r = 0; r < 4; r++) {
        float L = __shfl(tq, quad * 4 + r);    // row total lives at lane c16=row
        int token = q0 + wq * 32 + qs * 16 + quad * 4 + r;
        u16* orow = o + (size_t)(bb * NSEQ + token) * DIM + h * HDIM;
#pragma unroll
        for (int dt = 0; dt < 4; dt++)
          orow[dt * 16 + c16] = f2bf(Of[qs][dt][r] / L);
      }
    }
  }
}

// ---------------------------------------------------------------------------
extern "C" void kernel_launch(void* const* d_in, const int* in_sizes, int n_in,
                              void* d_out, int out_size, void* d_ws, size_t ws_size,
                              hipStream_t stream) {
  (void)in_sizes; (void)n_in; (void)out_size; (void)ws_size;
  const float* x      = (const float*)d_in[0];
  const float* ln1_g  = (const float*)d_in[1];
  const float* ln1_b  = (const float*)d_in[2];
  const float* w_qkv  = (const float*)d_in[3];
  const float* w_proj = (const float*)d_in[4];
  const float* b_proj = (const float*)d_in[5];
  const float* ln2_g  = (const float*)d_in[6];
  const float* ln2_b  = (const float*)d_in[7];
  const float* w_fc1  = (const float*)d_in[8];
  const float* b_fc1  = (const float*)d_in[9];
  const float* w_fc2  = (const float*)d_in[10];
  const float* b_fc2  = (const float*)d_in[11];
  float* out = (float*)d_out;   // f32 output (reference dtype)

  // ---- workspace layout: ~55.8 MiB total ----
  char* p = (char*)d_ws;
  u16* h_bf   = (u16*)p; p += (size_t)TOKENS * DIM * 2;     //  h, then h2
  u16* qkv_bf = (u16*)p; p += (size_t)TOKENS * QKV_N * 2;
  u16* o_bf   = (u16*)p; p += (size_t)TOKENS * DIM * 2;
  u16* x1_bf  = (u16*)p; p += (size_t)TOKENS * DIM * 2;     //  trunk
  u16* wprojT = (u16*)p; p += (size_t)DIM * DIM * 2;
  u16* wfc1T  = (u16*)p; p += (size_t)HID * DIM * 2;
  u16* wfc2T  = (u16*)p; p += (size_t)DIM * HID * 2;
  u16* wqkvT  = (u16*)p; p += (size_t)QKV_N * DIM * 2;
  u16* vtb    = (u16*)p; p += (size_t)TOKENS * DIM * 2;     //  V transposed
  u16* m_bf   = qkv_bf;  // fc1 out [4096,3072] overlays dead [qkv|o] exactly

  prep_kernel<<<dim3(1024 + 6912), 256, 0, stream>>>(
      x, ln1_g, ln1_b, h_bf,
      w_qkv, wqkvT, w_proj, wprojT, w_fc1, wfc1T, w_fc2, wfc2T);

  gemm_bt<64, 128, 0, 2, 0><<<dim3((QKV_N / 128) * (TOKENS / 64)), 256, 0, stream>>>(
      h_bf, wqkvT, qkv_bf, nullptr, nullptr, TOKENS, QKV_N, DIM, vtb);
  attn_kernel<<<dim3(2 * NHEAD * (NSEQ / 64)), 256, 0, stream>>>(qkv_bf, vtb, o_bf);
  gemm_bt<64, 64, 1, 2, 1><<<dim3((DIM / 64) * (TOKENS / 64)), 256, 0, stream>>>(
      o_bf, wprojT, x1_bf, b_proj, x, TOKENS, DIM, DIM, nullptr);
  ln_kernel<<<TOKENS / 4, 256, 0, stream>>>(x1_bf, ln2_g, ln2_b, h_bf);
  gemm_bt<64, 128, 2, 2, 0><<<dim3((HID / 128) * (TOKENS / 64)), 256, 0, stream>>>(
      h_bf, wfc1T, m_bf, b_fc1, nullptr, TOKENS, HID, DIM, nullptr);
  gemm_bt<64, 64, 3, 2, 1><<<dim3((DIM / 64) * (TOKENS / 64)), 256, 0, stream>>>(
      m_bf, wfc2T, out, b_fc2, x1_bf, TOKENS, DIM, HID, nullptr);
}